// Round 1
// baseline (509.762 us; speedup 1.0000x reference)
//
#include <hip/hip_runtime.h>
#include <hip/hip_bf16.h>
#include <math.h>

// Problem constants
#define Bb 4
#define Nn 512
#define Mm 64
#define Ff 256
#define Qq 16
#define Hh 8
#define Rr 32
#define Dd 32
#define FFNH 512
#define ROWS (Bb*Nn)          // 2048
#define KIN (Ff+Qq)           // 272
#define KOUT (2*Ff+Rr)        // 544

// ---------------------------------------------------------------- detect mask dtype
// bool layout: 131072 bytes, ~30% nonzero everywhere.
// int32 layout: values 0/1 -> bytes at (i%4)!=0 are all zero in first 131072 bytes.
__global__ void detect_mask(const unsigned char* __restrict__ mask, int* __restrict__ flag) {
    int tid = threadIdx.x;
    if (tid == 0) *flag = 0;
    __syncthreads();
    int found = 0;
    for (int i = tid; i < Bb*Nn*Mm; i += 256) {
        if ((i & 3) && mask[i]) { found = 1; break; }
    }
    if (found) atomicOr(flag, 1);
}

// ---------------------------------------------------------------- center = [a | charges]
__global__ void build_center(const float* __restrict__ a, const float* __restrict__ ch,
                             float* __restrict__ outp) {
    int i = blockIdx.x * 256 + threadIdx.x;
    if (i >= ROWS * KIN) return;
    int row = i / KIN, c = i - row * KIN;
    outp[i] = (c < Ff) ? a[row * Ff + c] : ch[row * Qq + (c - Ff)];
}

// ---------------------------------------------------------------- generic NT GEMM: C = A @ W^T + bias
// A: [Mr x K] row-major (stride K). W: [Nc x K] row-major. C row stride = ldc.
// tile 64x64, BK=16, 256 threads (16x16, 4x4 micro-tile each)
template<int GELU>
__global__ __launch_bounds__(256) void gemm_nt(const float* __restrict__ A,
                                               const float* __restrict__ W,
                                               const float* __restrict__ bias,
                                               float* __restrict__ C,
                                               int K, int ldc) {
    __shared__ float As[16][65];
    __shared__ float Bs[16][65];
    int tid = threadIdx.x;
    int tx = tid & 15, ty = tid >> 4;
    int rowbase = blockIdx.y * 64;
    int colbase = blockIdx.x * 64;
    float acc[4][4] = {};
    for (int kt = 0; kt < K; kt += 16) {
        #pragma unroll
        for (int i = tid; i < 64 * 16; i += 256) {
            int m = i >> 4, kk = i & 15;
            As[kk][m] = A[(size_t)(rowbase + m) * K + kt + kk];
        }
        #pragma unroll
        for (int i = tid; i < 64 * 16; i += 256) {
            int n = i >> 4, kk = i & 15;
            Bs[kk][n] = W[(size_t)(colbase + n) * K + kt + kk];
        }
        __syncthreads();
        #pragma unroll
        for (int kk = 0; kk < 16; ++kk) {
            float a0[4], b0[4];
            #pragma unroll
            for (int i = 0; i < 4; ++i) { a0[i] = As[kk][ty * 4 + i]; b0[i] = Bs[kk][tx * 4 + i]; }
            #pragma unroll
            for (int i = 0; i < 4; ++i)
                #pragma unroll
                for (int j = 0; j < 4; ++j) acc[i][j] = fmaf(a0[i], b0[j], acc[i][j]);
        }
        __syncthreads();
    }
    #pragma unroll
    for (int i = 0; i < 4; ++i) {
        int r = rowbase + ty * 4 + i;
        #pragma unroll
        for (int j = 0; j < 4; ++j) {
            int c = colbase + tx * 4 + j;
            float v = acc[i][j] + bias[c];
            if (GELU) v = 0.5f * v * (1.0f + erff(v * 0.70710678118654752f));
            C[(size_t)r * ldc + c] = v;
        }
    }
}

// ---------------------------------------------------------------- attention: one block per (b,n)
__global__ __launch_bounds__(256) void attn_kernel(const float* __restrict__ QKV,
                                                   const float* __restrict__ a,
                                                   const int* __restrict__ idx_j,
                                                   const float* __restrict__ d_ij,
                                                   const void* __restrict__ mask,
                                                   const float* __restrict__ shifts,
                                                   const float* __restrict__ Wrb,
                                                   const float* __restrict__ brb,
                                                   const int* __restrict__ flag,
                                                   float* __restrict__ U) {
    __shared__ float qs[Ff];
    __shared__ float rad[Mm][Rr];      // 8 KB
    __shared__ float att[Hh][Mm];      // scores, then attn
    __shared__ float attbar[Mm];
    __shared__ int   jl[Mm];
    __shared__ float shs[Rr];

    int row = blockIdx.x;
    int b = row >> 9;                  // N=512
    int tid = threadIdx.x;
    bool boolmask = (*flag != 0);

    if (tid < Mm) jl[tid] = idx_j[row * Mm + tid];
    if (tid < Rr) shs[tid] = shifts[tid];
    qs[tid] = QKV[(size_t)row * 768 + tid];
    __syncthreads();

    // radial basis exp(-4*(d - shift)^2)
    for (int i = tid; i < Mm * Rr; i += 256) {
        int m = i >> 5, r = i & 31;
        float d = d_ij[row * Mm + m];
        float t = d - shs[r];
        rad[m][r] = expf(-4.0f * t * t);
    }
    __syncthreads();

    // scores: 512 items (m,h)
    for (int it = tid; it < Mm * Hh; it += 256) {
        int m = it >> 3, h = it & 7;
        int mi = row * Mm + m;
        bool msk = boolmask ? (((const unsigned char*)mask)[mi] != 0)
                            : (((const int*)mask)[mi] != 0);
        float s;
        if (msk) {
            s = -INFINITY;
        } else {
            int j = jl[m];
            const float* kr = QKV + (size_t)(b * Nn + j) * 768 + 256 + h * 32;
            float acc = 0.f;
            #pragma unroll
            for (int d0 = 0; d0 < 32; ++d0) acc = fmaf(qs[h * 32 + d0], kr[d0], acc);
            acc *= 0.17677669529663687f;   // 1/sqrt(32)
            const float* wr = Wrb + h * Rr;
            float accr = 0.f;
            #pragma unroll
            for (int r = 0; r < Rr; ++r) accr = fmaf(rad[m][r], wr[r], accr);
            s = acc + accr + brb[h];
        }
        att[h][m] = s;
    }
    __syncthreads();

    // softmax over m per head: 32-lane subgroup per head, 2 m's per lane
    {
        int h = tid >> 5, l = tid & 31;
        float s0 = att[h][l], s1 = att[h][l + 32];
        float mx = fmaxf(s0, s1);
        #pragma unroll
        for (int off = 16; off; off >>= 1) mx = fmaxf(mx, __shfl_xor(mx, off, 32));
        float e0 = 0.f, e1 = 0.f;
        if (mx != -INFINITY) {
            e0 = expf(s0 - mx);
            e1 = expf(s1 - mx);
        }
        float sm = e0 + e1;
        #pragma unroll
        for (int off = 16; off; off >>= 1) sm += __shfl_xor(sm, off, 32);
        float inv = sm > 0.f ? 1.f / sm : 0.f;
        att[h][l] = e0 * inv;
        att[h][l + 32] = e1 * inv;
    }
    __syncthreads();

    if (tid < Mm) {
        float s = 0.f;
        #pragma unroll
        for (int h = 0; h < Hh; ++h) s += att[h][tid];
        attbar[tid] = s * 0.125f;
    }
    __syncthreads();

    // context: thread = h*32 + d
    {
        int h = tid >> 5, d0 = tid & 31;
        float acc = 0.f;
        for (int m = 0; m < Mm; ++m) {
            const float* vr = QKV + (size_t)(b * Nn + jl[m]) * 768 + 512;
            acc = fmaf(att[h][m], vr[h * 32 + d0], acc);
        }
        U[(size_t)row * KOUT + Ff + tid] = acc;
    }
    // radial context
    if (tid < Rr) {
        float acc = 0.f;
        for (int m = 0; m < Mm; ++m) acc = fmaf(attbar[m], rad[m][tid], acc);
        U[(size_t)row * KOUT + 2 * Ff + tid] = acc;
    }
    // copy a
    U[(size_t)row * KOUT + tid] = a[(size_t)row * Ff + tid];
}

// ---------------------------------------------------------------- residual + LayerNorm (one block per row)
__global__ __launch_bounds__(256) void add_ln(const float* __restrict__ x0,
                                              const float* __restrict__ dx,
                                              const float* __restrict__ g,
                                              const float* __restrict__ be,
                                              float* __restrict__ outp) {
    __shared__ float red[4];
    int row = blockIdx.x, tid = threadIdx.x;
    float v = x0[(size_t)row * Ff + tid] + dx[(size_t)row * Ff + tid];
    float s = v;
    #pragma unroll
    for (int off = 32; off; off >>= 1) s += __shfl_xor(s, off, 64);
    if ((tid & 63) == 0) red[tid >> 6] = s;
    __syncthreads();
    float mu = (red[0] + red[1] + red[2] + red[3]) * (1.f / Ff);
    float c = v - mu;
    float s2 = c * c;
    #pragma unroll
    for (int off = 32; off; off >>= 1) s2 += __shfl_xor(s2, off, 64);
    __syncthreads();
    if ((tid & 63) == 0) red[tid >> 6] = s2;
    __syncthreads();
    float var = (red[0] + red[1] + red[2] + red[3]) * (1.f / Ff);
    outp[(size_t)row * Ff + tid] = c * rsqrtf(var + 1e-5f) * g[tid] + be[tid];
}

// ---------------------------------------------------------------- launch
extern "C" void kernel_launch(void* const* d_in, const int* in_sizes, int n_in,
                              void* d_out, int out_size, void* d_ws, size_t ws_size,
                              hipStream_t stream) {
    const float* a       = (const float*)d_in[0];
    const float* charges = (const float*)d_in[1];
    const int*   idx_j   = (const int*)  d_in[2];
    const float* d_ij    = (const float*)d_in[3];
    const void*  mask    =               d_in[4];
    const float* shifts  = (const float*)d_in[5];
    const float* Wq   = (const float*)d_in[6];  const float* bq   = (const float*)d_in[7];
    const float* Wk   = (const float*)d_in[8];  const float* bk   = (const float*)d_in[9];
    const float* Wv   = (const float*)d_in[10]; const float* bv   = (const float*)d_in[11];
    const float* Wrb  = (const float*)d_in[12]; const float* brb  = (const float*)d_in[13];
    const float* Wout = (const float*)d_in[14]; const float* bout = (const float*)d_in[15];
    const float* g1   = (const float*)d_in[16]; const float* b1   = (const float*)d_in[17];
    const float* g2   = (const float*)d_in[18]; const float* b2   = (const float*)d_in[19];
    const float* Wf1  = (const float*)d_in[20]; const float* bf1  = (const float*)d_in[21];
    const float* Wf2  = (const float*)d_in[22]; const float* bf2  = (const float*)d_in[23];
    float* outp = (float*)d_out;

    float* ws   = (float*)d_ws;
    int*   flag = (int*)d_ws;
    // layout (floats): [0..1024) flag+pad | QKV slot 1,572,864 | U slot 1,114,112
    float* QKVb  = ws + 1024;                 // [2048 x 768] q|k|v
    float* Ubase = QKVb + (size_t)ROWS * 768; // [2048 x 544], also center / ffh
    float* center = Ubase;                    // dead before U written
    float* U      = Ubase;
    float* upd    = QKVb;                     // QKV dead after attention
    float* x      = QKVb + (size_t)ROWS * Ff;
    float* ff     = QKVb + (size_t)ROWS * Ff * 2;
    float* ffh    = Ubase;                    // U dead after Wout GEMM

    detect_mask<<<1, 256, 0, stream>>>((const unsigned char*)mask, flag);
    build_center<<<(ROWS * KIN + 255) / 256, 256, 0, stream>>>(a, charges, center);

    // QKV projections (fused output buffer, ldc=768)
    gemm_nt<0><<<dim3(Ff / 64, ROWS / 64), 256, 0, stream>>>(center, Wq, bq, QKVb + 0,   KIN, 768);
    gemm_nt<0><<<dim3(Ff / 64, ROWS / 64), 256, 0, stream>>>(center, Wk, bk, QKVb + 256, KIN, 768);
    gemm_nt<0><<<dim3(Ff / 64, ROWS / 64), 256, 0, stream>>>(center, Wv, bv, QKVb + 512, KIN, 768);

    attn_kernel<<<ROWS, 256, 0, stream>>>(QKVb, a, idx_j, d_ij, mask, shifts, Wrb, brb, flag, U);

    gemm_nt<0><<<dim3(Ff / 64, ROWS / 64), 256, 0, stream>>>(U, Wout, bout, upd, KOUT, Ff);
    add_ln<<<ROWS, 256, 0, stream>>>(a, upd, g1, b1, x);
    gemm_nt<1><<<dim3(FFNH / 64, ROWS / 64), 256, 0, stream>>>(x, Wf1, bf1, ffh, Ff, FFNH);
    gemm_nt<0><<<dim3(Ff / 64, ROWS / 64), 256, 0, stream>>>(ffh, Wf2, bf2, ff, FFNH, Ff);
    add_ln<<<ROWS, 256, 0, stream>>>(x, ff, g2, b2, outp);
}

// Round 2
// 275.926 us; speedup vs baseline: 1.8475x; 1.8475x over previous
//
#include <hip/hip_runtime.h>
#include <hip/hip_bf16.h>
#include <math.h>

// Problem constants
#define Bb 4
#define Nn 512
#define Mm 64
#define Ff 256
#define Qq 16
#define Hh 8
#define Rr 32
#define Dd 32
#define FFNH 512
#define ROWS (Bb*Nn)          // 2048
#define KIN (Ff+Qq)           // 272
#define KOUT (2*Ff+Rr)        // 544

// ---------------------------------------------------------------- detect mask dtype
// bool layout: 131072 bytes, ~30% nonzero everywhere.
// int32 layout: values 0/1 -> bytes at (i%4)!=0 are all zero in first 131072 bytes.
// Parallel: one byte per thread; racing plain stores of the same value are fine.
__global__ void detect_mask(const unsigned char* __restrict__ mask, int* __restrict__ flag) {
    int i = blockIdx.x * 256 + threadIdx.x;
    if (i < Bb*Nn*Mm && (i & 3) && mask[i]) *flag = 1;
}

// ---------------------------------------------------------------- fused QKV GEMM
// C[row, sel*256 + col] = [a|charges](row,:) @ Wsel^T + bsel
// grid: (12, 32); blockIdx.x: sel = x>>2 (q/k/v), col-tile = (x&3)*64
__global__ __launch_bounds__(256) void gemm_qkv(const float* __restrict__ a,
                                                const float* __restrict__ ch,
                                                const float* __restrict__ Wq,
                                                const float* __restrict__ Wk,
                                                const float* __restrict__ Wv,
                                                const float* __restrict__ bq,
                                                const float* __restrict__ bk,
                                                const float* __restrict__ bv,
                                                float* __restrict__ QKV) {
    __shared__ float As[16][65];
    __shared__ float Bs[16][65];
    int tid = threadIdx.x;
    int tx = tid & 15, ty = tid >> 4;
    int rowbase = blockIdx.y * 64;
    int sel = blockIdx.x >> 2;
    int colbase = (blockIdx.x & 3) * 64;
    const float* W    = sel == 0 ? Wq : (sel == 1 ? Wk : Wv);
    const float* bias = sel == 0 ? bq : (sel == 1 ? bk : bv);
    float acc[4][4] = {};
    for (int kt = 0; kt < KIN; kt += 16) {
        #pragma unroll
        for (int i = tid; i < 64 * 16; i += 256) {
            int m = i >> 4, kk = i & 15;
            int row = rowbase + m, c = kt + kk;
            As[kk][m] = (c < Ff) ? a[(size_t)row * Ff + c] : ch[(size_t)row * Qq + (c - Ff)];
        }
        #pragma unroll
        for (int i = tid; i < 64 * 16; i += 256) {
            int n = i >> 4, kk = i & 15;
            Bs[kk][n] = W[(size_t)(colbase + n) * KIN + kt + kk];
        }
        __syncthreads();
        #pragma unroll
        for (int kk = 0; kk < 16; ++kk) {
            float a0[4], b0[4];
            #pragma unroll
            for (int i = 0; i < 4; ++i) { a0[i] = As[kk][ty * 4 + i]; b0[i] = Bs[kk][tx * 4 + i]; }
            #pragma unroll
            for (int i = 0; i < 4; ++i)
                #pragma unroll
                for (int j = 0; j < 4; ++j) acc[i][j] = fmaf(a0[i], b0[j], acc[i][j]);
        }
        __syncthreads();
    }
    #pragma unroll
    for (int i = 0; i < 4; ++i) {
        int r = rowbase + ty * 4 + i;
        #pragma unroll
        for (int j = 0; j < 4; ++j) {
            int c = colbase + tx * 4 + j;
            QKV[(size_t)r * 768 + sel * 256 + c] = acc[i][j] + bias[c];
        }
    }
}

// ---------------------------------------------------------------- generic NT GEMM: C = A @ W^T + bias
template<int GELU>
__global__ __launch_bounds__(256) void gemm_nt(const float* __restrict__ A,
                                               const float* __restrict__ W,
                                               const float* __restrict__ bias,
                                               float* __restrict__ C,
                                               int K, int ldc) {
    __shared__ float As[16][65];
    __shared__ float Bs[16][65];
    int tid = threadIdx.x;
    int tx = tid & 15, ty = tid >> 4;
    int rowbase = blockIdx.y * 64;
    int colbase = blockIdx.x * 64;
    float acc[4][4] = {};
    for (int kt = 0; kt < K; kt += 16) {
        #pragma unroll
        for (int i = tid; i < 64 * 16; i += 256) {
            int m = i >> 4, kk = i & 15;
            As[kk][m] = A[(size_t)(rowbase + m) * K + kt + kk];
        }
        #pragma unroll
        for (int i = tid; i < 64 * 16; i += 256) {
            int n = i >> 4, kk = i & 15;
            Bs[kk][n] = W[(size_t)(colbase + n) * K + kt + kk];
        }
        __syncthreads();
        #pragma unroll
        for (int kk = 0; kk < 16; ++kk) {
            float a0[4], b0[4];
            #pragma unroll
            for (int i = 0; i < 4; ++i) { a0[i] = As[kk][ty * 4 + i]; b0[i] = Bs[kk][tx * 4 + i]; }
            #pragma unroll
            for (int i = 0; i < 4; ++i)
                #pragma unroll
                for (int j = 0; j < 4; ++j) acc[i][j] = fmaf(a0[i], b0[j], acc[i][j]);
        }
        __syncthreads();
    }
    #pragma unroll
    for (int i = 0; i < 4; ++i) {
        int r = rowbase + ty * 4 + i;
        #pragma unroll
        for (int j = 0; j < 4; ++j) {
            int c = colbase + tx * 4 + j;
            float v = acc[i][j] + bias[c];
            if (GELU) v = 0.5f * v * (1.0f + erff(v * 0.70710678118654752f));
            C[(size_t)r * ldc + c] = v;
        }
    }
}

// ---------------------------------------------------------------- attention: one block per (b,n)
__global__ __launch_bounds__(256) void attn_kernel(const float* __restrict__ QKV,
                                                   const float* __restrict__ a,
                                                   const int* __restrict__ idx_j,
                                                   const float* __restrict__ d_ij,
                                                   const void* __restrict__ mask,
                                                   const float* __restrict__ shifts,
                                                   const float* __restrict__ Wrb,
                                                   const float* __restrict__ brb,
                                                   const int* __restrict__ flag,
                                                   float* __restrict__ U) {
    __shared__ float qs[Ff];
    __shared__ float rad[Mm][Rr];      // 8 KB
    __shared__ float att[Hh][Mm];      // scores, then attn
    __shared__ float attbar[Mm];
    __shared__ int   jl[Mm];
    __shared__ float shs[Rr];

    int row = blockIdx.x;
    int b = row >> 9;                  // N=512
    int tid = threadIdx.x;
    bool boolmask = (*flag != 0);

    if (tid < Mm) jl[tid] = idx_j[row * Mm + tid];
    if (tid < Rr) shs[tid] = shifts[tid];
    qs[tid] = QKV[(size_t)row * 768 + tid];
    __syncthreads();

    // radial basis exp(-4*(d - shift)^2)
    for (int i = tid; i < Mm * Rr; i += 256) {
        int m = i >> 5, r = i & 31;
        float d = d_ij[row * Mm + m];
        float t = d - shs[r];
        rad[m][r] = expf(-4.0f * t * t);
    }
    __syncthreads();

    // scores: 512 items (m,h)
    for (int it = tid; it < Mm * Hh; it += 256) {
        int m = it >> 3, h = it & 7;
        int mi = row * Mm + m;
        bool msk = boolmask ? (((const unsigned char*)mask)[mi] != 0)
                            : (((const int*)mask)[mi] != 0);
        float s;
        if (msk) {
            s = -INFINITY;
        } else {
            int j = jl[m];
            const float* kr = QKV + (size_t)(b * Nn + j) * 768 + 256 + h * 32;
            float acc = 0.f;
            #pragma unroll
            for (int d0 = 0; d0 < 32; ++d0) acc = fmaf(qs[h * 32 + d0], kr[d0], acc);
            acc *= 0.17677669529663687f;   // 1/sqrt(32)
            const float* wr = Wrb + h * Rr;
            float accr = 0.f;
            #pragma unroll
            for (int r = 0; r < Rr; ++r) accr = fmaf(rad[m][r], wr[r], accr);
            s = acc + accr + brb[h];
        }
        att[h][m] = s;
    }
    __syncthreads();

    // softmax over m per head: 32-lane subgroup per head, 2 m's per lane
    {
        int h = tid >> 5, l = tid & 31;
        float s0 = att[h][l], s1 = att[h][l + 32];
        float mx = fmaxf(s0, s1);
        #pragma unroll
        for (int off = 16; off; off >>= 1) mx = fmaxf(mx, __shfl_xor(mx, off, 32));
        float e0 = 0.f, e1 = 0.f;
        if (mx != -INFINITY) {
            e0 = expf(s0 - mx);
            e1 = expf(s1 - mx);
        }
        float sm = e0 + e1;
        #pragma unroll
        for (int off = 16; off; off >>= 1) sm += __shfl_xor(sm, off, 32);
        float inv = sm > 0.f ? 1.f / sm : 0.f;
        att[h][l] = e0 * inv;
        att[h][l + 32] = e1 * inv;
    }
    __syncthreads();

    if (tid < Mm) {
        float s = 0.f;
        #pragma unroll
        for (int h = 0; h < Hh; ++h) s += att[h][tid];
        attbar[tid] = s * 0.125f;
    }
    __syncthreads();

    // context: thread = h*32 + d
    {
        int h = tid >> 5, d0 = tid & 31;
        float acc = 0.f;
        for (int m = 0; m < Mm; ++m) {
            const float* vr = QKV + (size_t)(b * Nn + jl[m]) * 768 + 512;
            acc = fmaf(att[h][m], vr[h * 32 + d0], acc);
        }
        U[(size_t)row * KOUT + Ff + tid] = acc;
    }
    // radial context
    if (tid < Rr) {
        float acc = 0.f;
        for (int m = 0; m < Mm; ++m) acc = fmaf(attbar[m], rad[m][tid], acc);
        U[(size_t)row * KOUT + 2 * Ff + tid] = acc;
    }
    // copy a
    U[(size_t)row * KOUT + tid] = a[(size_t)row * Ff + tid];
}

// ---------------------------------------------------------------- residual + LayerNorm (one block per row)
__global__ __launch_bounds__(256) void add_ln(const float* __restrict__ x0,
                                              const float* __restrict__ dx,
                                              const float* __restrict__ g,
                                              const float* __restrict__ be,
                                              float* __restrict__ outp) {
    __shared__ float red[4];
    int row = blockIdx.x, tid = threadIdx.x;
    float v = x0[(size_t)row * Ff + tid] + dx[(size_t)row * Ff + tid];
    float s = v;
    #pragma unroll
    for (int off = 32; off; off >>= 1) s += __shfl_xor(s, off, 64);
    if ((tid & 63) == 0) red[tid >> 6] = s;
    __syncthreads();
    float mu = (red[0] + red[1] + red[2] + red[3]) * (1.f / Ff);
    float c = v - mu;
    float s2 = c * c;
    #pragma unroll
    for (int off = 32; off; off >>= 1) s2 += __shfl_xor(s2, off, 64);
    __syncthreads();
    if ((tid & 63) == 0) red[tid >> 6] = s2;
    __syncthreads();
    float var = (red[0] + red[1] + red[2] + red[3]) * (1.f / Ff);
    outp[(size_t)row * Ff + tid] = c * rsqrtf(var + 1e-5f) * g[tid] + be[tid];
}

// ---------------------------------------------------------------- launch
extern "C" void kernel_launch(void* const* d_in, const int* in_sizes, int n_in,
                              void* d_out, int out_size, void* d_ws, size_t ws_size,
                              hipStream_t stream) {
    const float* a       = (const float*)d_in[0];
    const float* charges = (const float*)d_in[1];
    const int*   idx_j   = (const int*)  d_in[2];
    const float* d_ij    = (const float*)d_in[3];
    const void*  mask    =               d_in[4];
    const float* shifts  = (const float*)d_in[5];
    const float* Wq   = (const float*)d_in[6];  const float* bq   = (const float*)d_in[7];
    const float* Wk   = (const float*)d_in[8];  const float* bk   = (const float*)d_in[9];
    const float* Wv   = (const float*)d_in[10]; const float* bv   = (const float*)d_in[11];
    const float* Wrb  = (const float*)d_in[12]; const float* brb  = (const float*)d_in[13];
    const float* Wout = (const float*)d_in[14]; const float* bout = (const float*)d_in[15];
    const float* g1   = (const float*)d_in[16]; const float* b1   = (const float*)d_in[17];
    const float* g2   = (const float*)d_in[18]; const float* b2   = (const float*)d_in[19];
    const float* Wf1  = (const float*)d_in[20]; const float* bf1  = (const float*)d_in[21];
    const float* Wf2  = (const float*)d_in[22]; const float* bf2  = (const float*)d_in[23];
    float* outp = (float*)d_out;

    float* ws   = (float*)d_ws;
    int*   flag = (int*)d_ws;
    // layout (floats): [0..1024) flag+pad | QKV slot | U slot
    float* QKVb  = ws + 1024;                 // [2048 x 768] q|k|v
    float* Ubase = QKVb + (size_t)ROWS * 768; // [2048 x 544]
    float* U      = Ubase;
    float* upd    = QKVb;                     // QKV dead after attention
    float* x      = QKVb + (size_t)ROWS * Ff;
    float* ff     = QKVb + (size_t)ROWS * Ff * 2;
    float* ffh    = Ubase;                    // U dead after Wout GEMM

    hipMemsetAsync(flag, 0, sizeof(int), stream);
    detect_mask<<<(Bb*Nn*Mm) / 256, 256, 0, stream>>>((const unsigned char*)mask, flag);

    gemm_qkv<<<dim3(12, ROWS / 64), 256, 0, stream>>>(a, charges, Wq, Wk, Wv, bq, bk, bv, QKVb);

    attn_kernel<<<ROWS, 256, 0, stream>>>(QKVb, a, idx_j, d_ij, mask, shifts, Wrb, brb, flag, U);

    gemm_nt<0><<<dim3(Ff / 64, ROWS / 64), 256, 0, stream>>>(U, Wout, bout, upd, KOUT, Ff);
    add_ln<<<ROWS, 256, 0, stream>>>(a, upd, g1, b1, x);
    gemm_nt<1><<<dim3(FFNH / 64, ROWS / 64), 256, 0, stream>>>(x, Wf1, bf1, ffh, Ff, FFNH);
    gemm_nt<0><<<dim3(Ff / 64, ROWS / 64), 256, 0, stream>>>(ffh, Wf2, bf2, ff, FFNH, Ff);
    add_ln<<<ROWS, 256, 0, stream>>>(x, ff, g2, b2, outp);
}

// Round 3
// 149.690 us; speedup vs baseline: 3.4055x; 1.8433x over previous
//
#include <hip/hip_runtime.h>
#include <hip/hip_bf16.h>
#include <math.h>

// Problem constants
#define Bb 4
#define Nn 512
#define Mm 64
#define Ff 256
#define Qq 16
#define Hh 8
#define Rr 32
#define FFNH 512
#define ROWS (Bb*Nn)          // 2048
#define KIN (Ff+Qq)           // 272
#define KOUT (2*Ff+Rr)        // 544

// ---------------------------------------------------------------- detect mask dtype
__global__ void detect_mask(const unsigned char* __restrict__ mask, int* __restrict__ flag) {
    int i = blockIdx.x * 256 + threadIdx.x;
    if (i < Bb*Nn*Mm && (i & 3) && mask[i]) *flag = 1;
}

// ---------------------------------------------------------------- tiled GEMM, 64x64 tile, BK=32,
// double-buffered LDS, float4 loads, split-K via blockIdx.z.
// C = A @ W^T (+bias if ADD_BIAS). QKVMODE: A = [a|charges] concat, W selected from W0/W1/W2 by col block.
// grid: (colTiles, ROWS/64, SPLIT). Partial s written at C + s*pstride.
template<int KTOT, int SPLIT, int QKVMODE, int ADD_BIAS>
__global__ __launch_bounds__(256) void gemm64(const float* __restrict__ A,
                                              const float* __restrict__ A2,
                                              const float* __restrict__ W0,
                                              const float* __restrict__ W1,
                                              const float* __restrict__ W2,
                                              const float* __restrict__ b0p,
                                              const float* __restrict__ b1p,
                                              const float* __restrict__ b2p,
                                              float* __restrict__ C,
                                              int ldc, size_t pstride) {
    __shared__ float As[2][32][68];   // [buf][kk][row], 68-pad keeps b128 align + kills conflicts
    __shared__ float Bs[2][32][68];   // [buf][kk][col]
    int tid = threadIdx.x;
    int tx = tid & 15, ty = tid >> 4;
    int colbase = blockIdx.x * 64;
    int rowbase = blockIdx.y * 64;
    int s = blockIdx.z;
    constexpr int NT = (KTOT + 31) / 32;
    constexpr int TPER = (NT + SPLIT - 1) / SPLIT;
    int t0 = s * TPER;
    int t1 = (t0 + TPER < NT) ? (t0 + TPER) : NT;
    int NTloc = t1 - t0;

    const float* W = W0; const float* bias = b0p;
    int wrow0 = colbase;
    if (QKVMODE) {
        int sel = colbase >> 8;
        W    = sel == 0 ? W0 : (sel == 1 ? W1 : W2);
        bias = sel == 0 ? b0p : (sel == 1 ? b1p : b2p);
        wrow0 = colbase & 255;
    }

    float4 va[2], vb[2];
    auto loadTile = [&](int t) {
        int kt = t * 32;
        #pragma unroll
        for (int q = 0; q < 2; ++q) {
            int chunk = tid + q * 256;              // 512 chunks: 64 rows x 8 float4
            int r = chunk >> 3, c4 = (chunk & 7) * 4;
            int gc = kt + c4;
            float4 v = {0.f, 0.f, 0.f, 0.f};
            if (QKVMODE) {
                if (gc < Ff)      v = *reinterpret_cast<const float4*>(A  + (size_t)(rowbase + r) * Ff + gc);
                else if (gc < KIN) v = *reinterpret_cast<const float4*>(A2 + (size_t)(rowbase + r) * Qq + (gc - Ff));
            } else {
                if (gc < KTOT)    v = *reinterpret_cast<const float4*>(A  + (size_t)(rowbase + r) * KTOT + gc);
            }
            va[q] = v;
            float4 w = {0.f, 0.f, 0.f, 0.f};
            if (gc < KTOT) w = *reinterpret_cast<const float4*>(W + (size_t)(wrow0 + r) * KTOT + gc);
            vb[q] = w;
        }
    };
    auto writeLDS = [&](int buf) {
        #pragma unroll
        for (int q = 0; q < 2; ++q) {
            int chunk = tid + q * 256;
            int r = chunk >> 3, c4 = (chunk & 7) * 4;
            As[buf][c4 + 0][r] = va[q].x;
            As[buf][c4 + 1][r] = va[q].y;
            As[buf][c4 + 2][r] = va[q].z;
            As[buf][c4 + 3][r] = va[q].w;
            Bs[buf][c4 + 0][r] = vb[q].x;
            Bs[buf][c4 + 1][r] = vb[q].y;
            Bs[buf][c4 + 2][r] = vb[q].z;
            Bs[buf][c4 + 3][r] = vb[q].w;
        }
    };

    float acc[4][4] = {};
    loadTile(t0);
    writeLDS(0);
    __syncthreads();
    for (int tt = 0; tt < NTloc; ++tt) {
        if (tt + 1 < NTloc) loadTile(t0 + tt + 1);
        int buf = tt & 1;
        #pragma unroll
        for (int kk = 0; kk < 32; ++kk) {
            float4 a0 = *reinterpret_cast<const float4*>(&As[buf][kk][ty * 4]);
            float4 b0 = *reinterpret_cast<const float4*>(&Bs[buf][kk][tx * 4]);
            const float* ap = &a0.x; const float* bp = &b0.x;
            #pragma unroll
            for (int i = 0; i < 4; ++i)
                #pragma unroll
                for (int j = 0; j < 4; ++j) acc[i][j] = fmaf(ap[i], bp[j], acc[i][j]);
        }
        if (tt + 1 < NTloc) writeLDS((tt + 1) & 1);
        __syncthreads();
    }

    float* Cp = C + (size_t)s * pstride;
    #pragma unroll
    for (int i = 0; i < 4; ++i) {
        int r = rowbase + ty * 4 + i;
        float4 v;
        v.x = acc[i][0]; v.y = acc[i][1]; v.z = acc[i][2]; v.w = acc[i][3];
        if (ADD_BIAS) {
            v.x += bias[wrow0 + tx * 4 + 0];
            v.y += bias[wrow0 + tx * 4 + 1];
            v.z += bias[wrow0 + tx * 4 + 2];
            v.w += bias[wrow0 + tx * 4 + 3];
        }
        *reinterpret_cast<float4*>(Cp + (size_t)r * ldc + colbase + tx * 4) = v;
    }
}

// ---------------------------------------------------------------- attention: one block per (b,n)
__global__ __launch_bounds__(256) void attn_kernel(const float* __restrict__ QKV,
                                                   const float* __restrict__ a,
                                                   const int* __restrict__ idx_j,
                                                   const float* __restrict__ d_ij,
                                                   const void* __restrict__ mask,
                                                   const float* __restrict__ shifts,
                                                   const float* __restrict__ Wrb,
                                                   const float* __restrict__ brb,
                                                   const int* __restrict__ flag,
                                                   float* __restrict__ U) {
    __shared__ float qs[Ff];
    __shared__ float rad[Mm][Rr];
    __shared__ float att[Hh][Mm];
    __shared__ float attbar[Mm];
    __shared__ int   jl[Mm];
    __shared__ float shs[Rr];

    int row = blockIdx.x;
    int b = row >> 9;
    int tid = threadIdx.x;
    bool boolmask = (*flag != 0);

    if (tid < Mm) jl[tid] = idx_j[row * Mm + tid];
    if (tid < Rr) shs[tid] = shifts[tid];
    qs[tid] = QKV[(size_t)row * 768 + tid];
    __syncthreads();

    for (int i = tid; i < Mm * Rr; i += 256) {
        int m = i >> 5, r = i & 31;
        float d = d_ij[row * Mm + m];
        float t = d - shs[r];
        rad[m][r] = expf(-4.0f * t * t);
    }
    __syncthreads();

    for (int it = tid; it < Mm * Hh; it += 256) {
        int m = it >> 3, h = it & 7;
        int mi = row * Mm + m;
        bool msk = boolmask ? (((const unsigned char*)mask)[mi] != 0)
                            : (((const int*)mask)[mi] != 0);
        float sv;
        if (msk) {
            sv = -INFINITY;
        } else {
            int j = jl[m];
            const float* kr = QKV + (size_t)(b * Nn + j) * 768 + 256 + h * 32;
            float acc = 0.f;
            #pragma unroll
            for (int d0 = 0; d0 < 32; ++d0) acc = fmaf(qs[h * 32 + d0], kr[d0], acc);
            acc *= 0.17677669529663687f;
            const float* wr = Wrb + h * Rr;
            float accr = 0.f;
            #pragma unroll
            for (int r = 0; r < Rr; ++r) accr = fmaf(rad[m][r], wr[r], accr);
            sv = acc + accr + brb[h];
        }
        att[h][m] = sv;
    }
    __syncthreads();

    {
        int h = tid >> 5, l = tid & 31;
        float s0 = att[h][l], s1 = att[h][l + 32];
        float mx = fmaxf(s0, s1);
        #pragma unroll
        for (int off = 16; off; off >>= 1) mx = fmaxf(mx, __shfl_xor(mx, off, 32));
        float e0 = 0.f, e1 = 0.f;
        if (mx != -INFINITY) {
            e0 = expf(s0 - mx);
            e1 = expf(s1 - mx);
        }
        float sm = e0 + e1;
        #pragma unroll
        for (int off = 16; off; off >>= 1) sm += __shfl_xor(sm, off, 32);
        float inv = sm > 0.f ? 1.f / sm : 0.f;
        att[h][l] = e0 * inv;
        att[h][l + 32] = e1 * inv;
    }
    __syncthreads();

    if (tid < Mm) {
        float sv = 0.f;
        #pragma unroll
        for (int h = 0; h < Hh; ++h) sv += att[h][tid];
        attbar[tid] = sv * 0.125f;
    }
    __syncthreads();

    {
        int h = tid >> 5, d0 = tid & 31;
        float acc = 0.f;
        for (int m = 0; m < Mm; ++m) {
            const float* vr = QKV + (size_t)(b * Nn + jl[m]) * 768 + 512;
            acc = fmaf(att[h][m], vr[h * 32 + d0], acc);
        }
        U[(size_t)row * KOUT + Ff + tid] = acc;
    }
    if (tid < Rr) {
        float acc = 0.f;
        for (int m = 0; m < Mm; ++m) acc = fmaf(attbar[m], rad[m][tid], acc);
        U[(size_t)row * KOUT + 2 * Ff + tid] = acc;
    }
    U[(size_t)row * KOUT + tid] = a[(size_t)row * Ff + tid];
}

// ---------------------------------------------------------------- residual + bias + S partials + LayerNorm
template<int S>
__global__ __launch_bounds__(256) void add_ln_c(const float* __restrict__ x0,
                                                const float* __restrict__ part, size_t pstride,
                                                const float* __restrict__ bias,
                                                const float* __restrict__ g,
                                                const float* __restrict__ be,
                                                float* __restrict__ outp) {
    __shared__ float red[4];
    int row = blockIdx.x, tid = threadIdx.x;
    size_t off = (size_t)row * Ff + tid;
    float v = x0[off] + bias[tid];
    #pragma unroll
    for (int s = 0; s < S; ++s) v += part[(size_t)s * pstride + off];
    float sm = v;
    #pragma unroll
    for (int o = 32; o; o >>= 1) sm += __shfl_xor(sm, o, 64);
    if ((tid & 63) == 0) red[tid >> 6] = sm;
    __syncthreads();
    float mu = (red[0] + red[1] + red[2] + red[3]) * (1.f / Ff);
    float c = v - mu;
    float s2 = c * c;
    #pragma unroll
    for (int o = 32; o; o >>= 1) s2 += __shfl_xor(s2, o, 64);
    __syncthreads();
    if ((tid & 63) == 0) red[tid >> 6] = s2;
    __syncthreads();
    float var = (red[0] + red[1] + red[2] + red[3]) * (1.f / Ff);
    outp[off] = c * rsqrtf(var + 1e-5f) * g[tid] + be[tid];
}

// ---------------------------------------------------------------- combine FFN1 partials + bias + GELU
__global__ __launch_bounds__(256) void gelu_comb(const float* __restrict__ part, size_t pstride,
                                                 const float* __restrict__ bf1,
                                                 float* __restrict__ ffh) {
    size_t i = (size_t)blockIdx.x * 256 + threadIdx.x;
    float v = part[i] + part[pstride + i] + bf1[i & (FFNH - 1)];
    ffh[i] = 0.5f * v * (1.0f + erff(v * 0.70710678118654752f));
}

// ---------------------------------------------------------------- launch
extern "C" void kernel_launch(void* const* d_in, const int* in_sizes, int n_in,
                              void* d_out, int out_size, void* d_ws, size_t ws_size,
                              hipStream_t stream) {
    const float* a       = (const float*)d_in[0];
    const float* charges = (const float*)d_in[1];
    const int*   idx_j   = (const int*)  d_in[2];
    const float* d_ij    = (const float*)d_in[3];
    const void*  mask    =               d_in[4];
    const float* shifts  = (const float*)d_in[5];
    const float* Wq   = (const float*)d_in[6];  const float* bq   = (const float*)d_in[7];
    const float* Wk   = (const float*)d_in[8];  const float* bk   = (const float*)d_in[9];
    const float* Wv   = (const float*)d_in[10]; const float* bv   = (const float*)d_in[11];
    const float* Wrb  = (const float*)d_in[12]; const float* brb  = (const float*)d_in[13];
    const float* Wout = (const float*)d_in[14]; const float* bout = (const float*)d_in[15];
    const float* g1   = (const float*)d_in[16]; const float* b1   = (const float*)d_in[17];
    const float* g2   = (const float*)d_in[18]; const float* b2   = (const float*)d_in[19];
    const float* Wf1  = (const float*)d_in[20]; const float* bf1  = (const float*)d_in[21];
    const float* Wf2  = (const float*)d_in[22]; const float* bf2  = (const float*)d_in[23];
    float* outp = (float*)d_out;

    float* ws   = (float*)d_ws;
    int*   flag = (int*)d_ws;
    // ws layout (floats): flag(1024) | slot0: QKVb -> {x, ffh} (1,572,864) | U (1,114,112) | part (2,097,152)
    float* QKVb = ws + 1024;
    float* xbuf = QKVb;                       // reuses QKV slot after attention
    float* ffh  = QKVb + (size_t)ROWS * Ff;   // after xbuf within slot0
    float* U    = QKVb + (size_t)ROWS * 768;
    float* part = U + (size_t)ROWS * KOUT;

    hipMemsetAsync(flag, 0, sizeof(int), stream);
    detect_mask<<<(Bb*Nn*Mm) / 256, 256, 0, stream>>>((const unsigned char*)mask, flag);

    // QKV: [2048 x 768], K=272, no split, bias in epilogue
    gemm64<KIN, 1, 1, 1><<<dim3(12, 32, 1), 256, 0, stream>>>(
        a, charges, Wq, Wk, Wv, bq, bk, bv, QKVb, 768, 0);

    attn_kernel<<<ROWS, 256, 0, stream>>>(QKVb, a, idx_j, d_ij, mask, shifts, Wrb, brb, flag, U);

    // Wout: [2048 x 256], K=544, split 4
    gemm64<KOUT, 4, 0, 0><<<dim3(4, 32, 4), 256, 0, stream>>>(
        U, nullptr, Wout, nullptr, nullptr, nullptr, nullptr, nullptr, part, Ff, (size_t)ROWS * Ff);
    add_ln_c<4><<<ROWS, 256, 0, stream>>>(a, part, (size_t)ROWS * Ff, bout, g1, b1, xbuf);

    // FFN1: [2048 x 512], K=256, split 2
    gemm64<Ff, 2, 0, 0><<<dim3(8, 32, 2), 256, 0, stream>>>(
        xbuf, nullptr, Wf1, nullptr, nullptr, nullptr, nullptr, nullptr, part, FFNH, (size_t)ROWS * FFNH);
    gelu_comb<<<ROWS * FFNH / 256, 256, 0, stream>>>(part, (size_t)ROWS * FFNH, bf1, ffh);

    // FFN2: [2048 x 256], K=512, split 4
    gemm64<FFNH, 4, 0, 0><<<dim3(4, 32, 4), 256, 0, stream>>>(
        ffh, nullptr, Wf2, nullptr, nullptr, nullptr, nullptr, nullptr, part, Ff, (size_t)ROWS * Ff);
    add_ln_c<4><<<ROWS, 256, 0, stream>>>(xbuf, part, (size_t)ROWS * Ff, bf2, g2, b2, outp);
}

// Round 4
// 93.375 us; speedup vs baseline: 5.4593x; 1.6031x over previous
//
#include <hip/hip_runtime.h>
#include <hip/hip_bf16.h>
#include <math.h>

// Problem constants
#define Bb 4
#define Nn 512
#define Mm 64
#define Ff 256
#define Qq 16
#define Hh 8
#define Rr 32
#define FFNH 512
#define ROWS (Bb*Nn)          // 2048
#define KIN (Ff+Qq)           // 272
#define KINP 288              // padded to 9*32
#define KOUT (2*Ff+Rr)        // 544 = 17*32

typedef short short8 __attribute__((ext_vector_type(8)));
typedef float f32x4 __attribute__((ext_vector_type(4)));

__device__ inline unsigned short f2b(float f) {
    union { float f; unsigned u; } c; c.f = f;
    unsigned r = c.u + 0x7fffu + ((c.u >> 16) & 1u);
    return (unsigned short)(r >> 16);
}

// ---------------------------------------------------------------- detect mask dtype
__global__ void detect_mask(const unsigned char* __restrict__ mask, int* __restrict__ flag) {
    int i = blockIdx.x * 256 + threadIdx.x;
    if (i < Bb*Nn*Mm && (i & 3) && mask[i]) *flag = 1;
}

// ---------------------------------------------------------------- convert inputs/weights to bf16 arena
// segments (ushort offsets within arena):
// centerb [2048][288] | Wqkvb [768][288] | Woutb [256][544] | Wf1b [512][256] | Wf2b [256][512]
#define OFF_CENTER 0
#define OFF_WQKV   (OFF_CENTER + ROWS*KINP)            // 589824
#define OFF_WOUT   (OFF_WQKV + 768*KINP)               // 811008
#define OFF_WF1    (OFF_WOUT + Ff*KOUT)                // 950272
#define OFF_WF2    (OFF_WF1 + FFNH*Ff)                 // 1081344
#define OFF_U      (OFF_WF2 + Ff*FFNH)                 // 1212416
#define OFF_XB     (OFF_U + ROWS*KOUT)                 // 2326528
#define OFF_FFH    (OFF_XB + ROWS*Ff)                  // 2850816
#define ARENA_END  (OFF_FFH + ROWS*FFNH)               // 3899392 ushorts
#define CONV_TOTAL OFF_U                               // 1212416 elements to convert

__global__ __launch_bounds__(256) void to_bf16_all(const float* __restrict__ a,
                                                   const float* __restrict__ ch,
                                                   const float* __restrict__ Wq,
                                                   const float* __restrict__ Wk,
                                                   const float* __restrict__ Wv,
                                                   const float* __restrict__ Wout,
                                                   const float* __restrict__ Wf1,
                                                   const float* __restrict__ Wf2,
                                                   unsigned short* __restrict__ arena) {
    int i = blockIdx.x * 256 + threadIdx.x;
    float v;
    if (i < OFF_WQKV) {
        int row = i / KINP, c = i - row * KINP;
        v = (c < Ff) ? a[(size_t)row * Ff + c] : (c < KIN ? ch[(size_t)row * Qq + (c - Ff)] : 0.f);
    } else if (i < OFF_WOUT) {
        int j = i - OFF_WQKV;
        int n = j / KINP, c = j - n * KINP;
        const float* W = n < 256 ? Wq : (n < 512 ? Wk : Wv);
        int nr = n & 255;
        v = (c < KIN) ? W[(size_t)nr * KIN + c] : 0.f;
    } else if (i < OFF_WF1) {
        int j = i - OFF_WOUT;
        v = Wout[j];
    } else if (i < OFF_WF2) {
        int j = i - OFF_WF1;
        v = Wf1[j];
    } else {
        int j = i - OFF_WF2;
        v = Wf2[j];
    }
    arena[i] = f2b(v);
}

// ---------------------------------------------------------------- MFMA GEMM: C = A(bf16) @ W(bf16)^T
// A: [M][lda] ushort-bf16, W: [N][ldw], C fp32 [M][ldc] (+pstride for split-K partials)
// 64x64 tile, 4 waves (2x2 of 32x32), BK=32, double-buffered swizzled LDS.
// BIASQKV: add bias selected from b0/b1/b2 by col block of 256.
template<int KT, int SPLIT, int BIASQKV>
__global__ __launch_bounds__(256) void gemm_mfma(const unsigned short* __restrict__ Ab, int lda,
                                                 const unsigned short* __restrict__ Wb, int ldw,
                                                 const float* __restrict__ b0,
                                                 const float* __restrict__ b1,
                                                 const float* __restrict__ b2,
                                                 float* __restrict__ C, int ldc,
                                                 size_t pstride) {
    __shared__ unsigned short As[2][64][32];
    __shared__ unsigned short Bs[2][64][32];
    int tid = threadIdx.x;
    int colbase = blockIdx.x * 64;
    int rowbase = blockIdx.y * 64;
    constexpr int TPER = (KT + SPLIT - 1) / SPLIT;
    int t0 = blockIdx.z * TPER;
    int NL = KT - t0; if (NL > TPER) NL = TPER;

    // staging: thread -> (row sr, 16B slot sl)
    int sr = tid >> 2, sl = tid & 3;
    const unsigned short* Ap = Ab + (size_t)(rowbase + sr) * lda + sl * 8;
    const unsigned short* Wp = Wb + (size_t)(colbase + sr) * ldw + sl * 8;
    int ssw = (sl ^ (sr & 3)) * 8;

    // frags: wave quadrant
    int wave = tid >> 6, lane = tid & 63;
    int wr = (wave >> 1) * 32, wc = (wave & 1) * 32;
    int lrow = lane & 15;
    int kslot = lane >> 4;
    int sp = (kslot ^ (lane & 3)) * 8;   // row&3 == lane&3 for all frag rows

    uint4 av, wv;
    auto prefetch = [&](int t) {
        av = *reinterpret_cast<const uint4*>(Ap + (size_t)t * 32);
        wv = *reinterpret_cast<const uint4*>(Wp + (size_t)t * 32);
    };
    auto writeLDS = [&](int buf) {
        *reinterpret_cast<uint4*>(&As[buf][sr][ssw]) = av;
        *reinterpret_cast<uint4*>(&Bs[buf][sr][ssw]) = wv;
    };

    f32x4 acc[2][2] = {};
    prefetch(t0);
    writeLDS(0);
    __syncthreads();
    for (int tt = 0; tt < NL; ++tt) {
        if (tt + 1 < NL) prefetch(t0 + tt + 1);
        int buf = tt & 1;
        short8 a0 = *reinterpret_cast<const short8*>(&As[buf][wr + lrow][sp]);
        short8 a1 = *reinterpret_cast<const short8*>(&As[buf][wr + 16 + lrow][sp]);
        short8 bv0 = *reinterpret_cast<const short8*>(&Bs[buf][wc + lrow][sp]);
        short8 bv1 = *reinterpret_cast<const short8*>(&Bs[buf][wc + 16 + lrow][sp]);
        acc[0][0] = __builtin_amdgcn_mfma_f32_16x16x32_bf16(a0, bv0, acc[0][0], 0, 0, 0);
        acc[0][1] = __builtin_amdgcn_mfma_f32_16x16x32_bf16(a0, bv1, acc[0][1], 0, 0, 0);
        acc[1][0] = __builtin_amdgcn_mfma_f32_16x16x32_bf16(a1, bv0, acc[1][0], 0, 0, 0);
        acc[1][1] = __builtin_amdgcn_mfma_f32_16x16x32_bf16(a1, bv1, acc[1][1], 0, 0, 0);
        if (tt + 1 < NL) {
            writeLDS((tt + 1) & 1);
            __syncthreads();
        }
    }

    const float* bias = nullptr;
    if (BIASQKV) {
        int sel = colbase >> 8;
        bias = sel == 0 ? b0 : (sel == 1 ? b1 : b2);
    }
    float* Cp = C + (size_t)blockIdx.z * pstride;
    int colq = (colbase & 255);
    #pragma unroll
    for (int fr = 0; fr < 2; ++fr) {
        #pragma unroll
        for (int fc = 0; fc < 2; ++fc) {
            int col = colbase + wc + fc * 16 + (lane & 15);
            float badd = BIASQKV ? bias[colq + wc + fc * 16 + (lane & 15)] : 0.f;
            #pragma unroll
            for (int i = 0; i < 4; ++i) {
                int row = rowbase + wr + fr * 16 + (lane >> 4) * 4 + i;
                Cp[(size_t)row * ldc + col] = acc[fr][fc][i] + badd;
            }
        }
    }
}

// ---------------------------------------------------------------- attention: one block per (b,n)
__global__ __launch_bounds__(256) void attn_kernel(const float* __restrict__ QKV,
                                                   const float* __restrict__ a,
                                                   const int* __restrict__ idx_j,
                                                   const float* __restrict__ d_ij,
                                                   const void* __restrict__ mask,
                                                   const float* __restrict__ shifts,
                                                   const float* __restrict__ Wrb,
                                                   const float* __restrict__ brb,
                                                   const int* __restrict__ flag,
                                                   unsigned short* __restrict__ Ub) {
    __shared__ float qs[Ff];
    __shared__ float rad[Mm][Rr];
    __shared__ float att[Hh][Mm];
    __shared__ float attbar[Mm];
    __shared__ int   jl[Mm];
    __shared__ float shs[Rr];

    int row = blockIdx.x;
    int b = row >> 9;
    int tid = threadIdx.x;
    bool boolmask = (*flag != 0);

    if (tid < Mm) jl[tid] = idx_j[row * Mm + tid];
    if (tid < Rr) shs[tid] = shifts[tid];
    qs[tid] = QKV[(size_t)row * 768 + tid];
    __syncthreads();

    for (int i = tid; i < Mm * Rr; i += 256) {
        int m = i >> 5, r = i & 31;
        float d = d_ij[row * Mm + m];
        float t = d - shs[r];
        rad[m][r] = expf(-4.0f * t * t);
    }
    __syncthreads();

    for (int it = tid; it < Mm * Hh; it += 256) {
        int m = it >> 3, h = it & 7;
        int mi = row * Mm + m;
        bool msk = boolmask ? (((const unsigned char*)mask)[mi] != 0)
                            : (((const int*)mask)[mi] != 0);
        float sv;
        if (msk) {
            sv = -INFINITY;
        } else {
            int j = jl[m];
            const float* kr = QKV + (size_t)(b * Nn + j) * 768 + 256 + h * 32;
            float acc = 0.f;
            #pragma unroll
            for (int d0 = 0; d0 < 32; ++d0) acc = fmaf(qs[h * 32 + d0], kr[d0], acc);
            acc *= 0.17677669529663687f;
            const float* wr = Wrb + h * Rr;
            float accr = 0.f;
            #pragma unroll
            for (int r = 0; r < Rr; ++r) accr = fmaf(rad[m][r], wr[r], accr);
            sv = acc + accr + brb[h];
        }
        att[h][m] = sv;
    }
    __syncthreads();

    {
        int h = tid >> 5, l = tid & 31;
        float s0 = att[h][l], s1 = att[h][l + 32];
        float mx = fmaxf(s0, s1);
        #pragma unroll
        for (int off = 16; off; off >>= 1) mx = fmaxf(mx, __shfl_xor(mx, off, 32));
        float e0 = 0.f, e1 = 0.f;
        if (mx != -INFINITY) {
            e0 = expf(s0 - mx);
            e1 = expf(s1 - mx);
        }
        float sm = e0 + e1;
        #pragma unroll
        for (int off = 16; off; off >>= 1) sm += __shfl_xor(sm, off, 32);
        float inv = sm > 0.f ? 1.f / sm : 0.f;
        att[h][l] = e0 * inv;
        att[h][l + 32] = e1 * inv;
    }
    __syncthreads();

    if (tid < Mm) {
        float sv = 0.f;
        #pragma unroll
        for (int h = 0; h < Hh; ++h) sv += att[h][tid];
        attbar[tid] = sv * 0.125f;
    }
    __syncthreads();

    {
        int h = tid >> 5, d0 = tid & 31;
        float acc = 0.f;
        for (int m = 0; m < Mm; ++m) {
            const float* vr = QKV + (size_t)(b * Nn + jl[m]) * 768 + 512;
            acc = fmaf(att[h][m], vr[h * 32 + d0], acc);
        }
        Ub[(size_t)row * KOUT + Ff + tid] = f2b(acc);
    }
    if (tid < Rr) {
        float acc = 0.f;
        for (int m = 0; m < Mm; ++m) acc = fmaf(attbar[m], rad[m][tid], acc);
        Ub[(size_t)row * KOUT + 2 * Ff + tid] = f2b(acc);
    }
    Ub[(size_t)row * KOUT + tid] = f2b(a[(size_t)row * Ff + tid]);
}

// ---------------------------------------------------------------- residual + bias + S partials + LayerNorm
template<int S, int WB>
__global__ __launch_bounds__(256) void add_ln_c(const float* __restrict__ x0,
                                                const float* __restrict__ part, size_t pstride,
                                                const float* __restrict__ bias,
                                                const float* __restrict__ g,
                                                const float* __restrict__ be,
                                                float* __restrict__ outp,
                                                unsigned short* __restrict__ xb) {
    __shared__ float red[4];
    int row = blockIdx.x, tid = threadIdx.x;
    size_t off = (size_t)row * Ff + tid;
    float v = x0[off] + bias[tid];
    #pragma unroll
    for (int s = 0; s < S; ++s) v += part[(size_t)s * pstride + off];
    float sm = v;
    #pragma unroll
    for (int o = 32; o; o >>= 1) sm += __shfl_xor(sm, o, 64);
    if ((tid & 63) == 0) red[tid >> 6] = sm;
    __syncthreads();
    float mu = (red[0] + red[1] + red[2] + red[3]) * (1.f / Ff);
    float c = v - mu;
    float s2 = c * c;
    #pragma unroll
    for (int o = 32; o; o >>= 1) s2 += __shfl_xor(s2, o, 64);
    __syncthreads();
    if ((tid & 63) == 0) red[tid >> 6] = s2;
    __syncthreads();
    float var = (red[0] + red[1] + red[2] + red[3]) * (1.f / Ff);
    float res = c * rsqrtf(var + 1e-5f) * g[tid] + be[tid];
    outp[off] = res;
    if (WB) xb[off] = f2b(res);
}

// ---------------------------------------------------------------- combine FFN1 partials + bias + GELU -> bf16
__global__ __launch_bounds__(256) void gelu_comb(const float* __restrict__ part, size_t pstride,
                                                 const float* __restrict__ bf1,
                                                 unsigned short* __restrict__ ffhb) {
    size_t i = (size_t)blockIdx.x * 256 + threadIdx.x;
    float v = part[i] + part[pstride + i] + bf1[i & (FFNH - 1)];
    ffhb[i] = f2b(0.5f * v * (1.0f + erff(v * 0.70710678118654752f)));
}

// ---------------------------------------------------------------- launch
extern "C" void kernel_launch(void* const* d_in, const int* in_sizes, int n_in,
                              void* d_out, int out_size, void* d_ws, size_t ws_size,
                              hipStream_t stream) {
    const float* a       = (const float*)d_in[0];
    const float* charges = (const float*)d_in[1];
    const int*   idx_j   = (const int*)  d_in[2];
    const float* d_ij    = (const float*)d_in[3];
    const void*  mask    =               d_in[4];
    const float* shifts  = (const float*)d_in[5];
    const float* Wq   = (const float*)d_in[6];  const float* bq   = (const float*)d_in[7];
    const float* Wk   = (const float*)d_in[8];  const float* bk   = (const float*)d_in[9];
    const float* Wv   = (const float*)d_in[10]; const float* bv   = (const float*)d_in[11];
    const float* Wrb  = (const float*)d_in[12]; const float* brb  = (const float*)d_in[13];
    const float* Wout = (const float*)d_in[14]; const float* bout = (const float*)d_in[15];
    const float* g1   = (const float*)d_in[16]; const float* b1   = (const float*)d_in[17];
    const float* g2   = (const float*)d_in[18]; const float* b2   = (const float*)d_in[19];
    const float* Wf1  = (const float*)d_in[20]; const float* bf1  = (const float*)d_in[21];
    const float* Wf2  = (const float*)d_in[22]; const float* bf2  = (const float*)d_in[23];
    float* outp = (float*)d_out;

    float* ws   = (float*)d_ws;
    int*   flag = (int*)d_ws;
    // ws layout (floats): flag(1024) | shared slot QKVb/part (2,097,152) | xbuf (524,288) | bf16 arena
    float* QKVb = ws + 1024;                       // [2048 x 768] fp32 (dead after attn)
    float* part = QKVb;                            // split-K partials reuse the slot
    float* xbuf = QKVb + 2097152;                  // [2048 x 256] fp32
    unsigned short* arena = (unsigned short*)(xbuf + (size_t)ROWS * Ff);
    unsigned short* centerb = arena + OFF_CENTER;
    unsigned short* Wqkvb   = arena + OFF_WQKV;
    unsigned short* Woutb   = arena + OFF_WOUT;
    unsigned short* Wf1b    = arena + OFF_WF1;
    unsigned short* Wf2b    = arena + OFF_WF2;
    unsigned short* Ub      = arena + OFF_U;
    unsigned short* xb      = arena + OFF_XB;
    unsigned short* ffhb    = arena + OFF_FFH;

    hipMemsetAsync(flag, 0, sizeof(int), stream);
    detect_mask<<<(Bb*Nn*Mm) / 256, 256, 0, stream>>>((const unsigned char*)mask, flag);

    to_bf16_all<<<CONV_TOTAL / 256, 256, 0, stream>>>(a, charges, Wq, Wk, Wv, Wout, Wf1, Wf2, arena);

    // QKV: [2048 x 768] = centerb @ Wqkvb^T, K=288 (9 tiles), bias per 256-col block
    gemm_mfma<9, 1, 1><<<dim3(12, 32, 1), 256, 0, stream>>>(
        centerb, KINP, Wqkvb, KINP, bq, bk, bv, QKVb, 768, 0);

    attn_kernel<<<ROWS, 256, 0, stream>>>(QKVb, a, idx_j, d_ij, mask, shifts, Wrb, brb, flag, Ub);

    // Wout: [2048 x 256], K=544 (17 tiles), split 4
    gemm_mfma<17, 4, 0><<<dim3(4, 32, 4), 256, 0, stream>>>(
        Ub, KOUT, Woutb, KOUT, nullptr, nullptr, nullptr, part, Ff, (size_t)ROWS * Ff);
    add_ln_c<4, 1><<<ROWS, 256, 0, stream>>>(a, part, (size_t)ROWS * Ff, bout, g1, b1, xbuf, xb);

    // FFN1: [2048 x 512], K=256 (8 tiles), split 2
    gemm_mfma<8, 2, 0><<<dim3(8, 32, 2), 256, 0, stream>>>(
        xb, Ff, Wf1b, Ff, nullptr, nullptr, nullptr, part, FFNH, (size_t)ROWS * FFNH);
    gelu_comb<<<ROWS * FFNH / 256, 256, 0, stream>>>(part, (size_t)ROWS * FFNH, bf1, ffhb);

    // FFN2: [2048 x 256], K=512 (16 tiles), split 4
    gemm_mfma<16, 4, 0><<<dim3(4, 32, 4), 256, 0, stream>>>(
        ffhb, FFNH, Wf2b, FFNH, nullptr, nullptr, nullptr, part, Ff, (size_t)ROWS * Ff);
    add_ln_c<4, 0><<<ROWS, 256, 0, stream>>>(xbuf, part, (size_t)ROWS * Ff, bf2, g2, b2, outp, nullptr);
}

// Round 5
// 92.806 us; speedup vs baseline: 5.4928x; 1.0061x over previous
//
#include <hip/hip_runtime.h>
#include <hip/hip_bf16.h>
#include <math.h>

// Problem constants
#define Bb 4
#define Nn 512
#define Mm 64
#define Ff 256
#define Qq 16
#define Hh 8
#define Rr 32
#define FFNH 512
#define ROWS (Bb*Nn)          // 2048
#define KIN (Ff+Qq)           // 272
#define KINP 288              // padded to 9*32
#define KOUT (2*Ff+Rr)        // 544 = 17*32

typedef short short8 __attribute__((ext_vector_type(8)));
typedef float f32x4 __attribute__((ext_vector_type(4)));

__device__ inline unsigned short f2b(float f) {
    union { float f; unsigned u; } c; c.f = f;
    unsigned r = c.u + 0x7fffu + ((c.u >> 16) & 1u);
    return (unsigned short)(r >> 16);
}

// arena segments (ushort offsets)
#define OFF_CENTER 0
#define OFF_WQKV   (OFF_CENTER + ROWS*KINP)            // 589824
#define OFF_WOUT   (OFF_WQKV + 768*KINP)               // 811008
#define OFF_WF1    (OFF_WOUT + Ff*KOUT)                // 950272
#define OFF_WF2    (OFF_WF1 + FFNH*Ff)                 // 1081344
#define OFF_U      (OFF_WF2 + Ff*FFNH)                 // 1212416
#define OFF_XB     (OFF_U + ROWS*KOUT)                 // 2326528
#define OFF_FFH    (OFF_XB + ROWS*Ff)                  // 2850816
#define CONV_TOTAL OFF_U                               // 1212416
#define CONV_BLK   (CONV_TOTAL/256)                    // 4736
#define A2U_BLK    (ROWS*Ff/256)                       // 2048
#define MSK_BLK    (Bb*Nn*Mm/256)                      // 512

// ---------------------------------------------------------------- prep: convert + U[:, :256]=bf16(a) + detect mask
__global__ __launch_bounds__(256) void prep(const float* __restrict__ a,
                                            const float* __restrict__ ch,
                                            const float* __restrict__ Wq,
                                            const float* __restrict__ Wk,
                                            const float* __restrict__ Wv,
                                            const float* __restrict__ Wout,
                                            const float* __restrict__ Wf1,
                                            const float* __restrict__ Wf2,
                                            const unsigned char* __restrict__ mask,
                                            int* __restrict__ flag,
                                            unsigned short* __restrict__ arena) {
    int bid = blockIdx.x, tid = threadIdx.x;
    if (bid < CONV_BLK) {
        int i = bid * 256 + tid;
        float v;
        if (i < OFF_WQKV) {
            int row = i / KINP, c = i - row * KINP;
            v = (c < Ff) ? a[(size_t)row * Ff + c] : (c < KIN ? ch[(size_t)row * Qq + (c - Ff)] : 0.f);
        } else if (i < OFF_WOUT) {
            int j = i - OFF_WQKV;
            int n = j / KINP, c = j - n * KINP;
            const float* W = n < 256 ? Wq : (n < 512 ? Wk : Wv);
            int nr = n & 255;
            v = (c < KIN) ? W[(size_t)nr * KIN + c] : 0.f;
        } else if (i < OFF_WF1) {
            v = Wout[i - OFF_WOUT];
        } else if (i < OFF_WF2) {
            v = Wf1[i - OFF_WF1];
        } else {
            v = Wf2[i - OFF_WF2];
        }
        arena[i] = f2b(v);
    } else if (bid < CONV_BLK + A2U_BLK) {
        int j = (bid - CONV_BLK) * 256 + tid;
        int row = j >> 8, col = j & 255;
        arena[OFF_U + (size_t)row * KOUT + col] = f2b(a[j]);
    } else {
        int i = (bid - CONV_BLK - A2U_BLK) * 256 + tid;
        if ((i & 3) && mask[i]) *flag = 1;
    }
}

// ---------------------------------------------------------------- MFMA GEMM: C = A(bf16) @ W(bf16)^T
// MODE 0: fp32 out (split-K partials via blockIdx.z, no bias)
// MODE 1: fp32 out + bias selected from b0/b1/b2 per 256-col block (QKV)
// MODE 2: bias b0 + exact GELU -> bf16 out Cb
template<int KT, int SPLIT, int MODE>
__global__ __launch_bounds__(256) void gemm_mfma(const unsigned short* __restrict__ Ab, int lda,
                                                 const unsigned short* __restrict__ Wb, int ldw,
                                                 const float* __restrict__ b0,
                                                 const float* __restrict__ b1,
                                                 const float* __restrict__ b2,
                                                 float* __restrict__ C,
                                                 unsigned short* __restrict__ Cb,
                                                 int ldc, size_t pstride) {
    __shared__ unsigned short As[2][64][32];
    __shared__ unsigned short Bs[2][64][32];
    int tid = threadIdx.x;
    int colbase = blockIdx.x * 64;
    int rowbase = blockIdx.y * 64;
    constexpr int TPER = (KT + SPLIT - 1) / SPLIT;
    int t0 = blockIdx.z * TPER;
    int NL = KT - t0; if (NL > TPER) NL = TPER;

    int sr = tid >> 2, sl = tid & 3;
    const unsigned short* Ap = Ab + (size_t)(rowbase + sr) * lda + sl * 8;
    const unsigned short* Wp = Wb + (size_t)(colbase + sr) * ldw + sl * 8;
    int ssw = (sl ^ (sr & 3)) * 8;

    int wave = tid >> 6, lane = tid & 63;
    int wr = (wave >> 1) * 32, wc = (wave & 1) * 32;
    int lrow = lane & 15;
    int kslot = lane >> 4;
    int sp = (kslot ^ (lane & 3)) * 8;

    uint4 av, wv;
    auto prefetch = [&](int t) {
        av = *reinterpret_cast<const uint4*>(Ap + (size_t)t * 32);
        wv = *reinterpret_cast<const uint4*>(Wp + (size_t)t * 32);
    };
    auto writeLDS = [&](int buf) {
        *reinterpret_cast<uint4*>(&As[buf][sr][ssw]) = av;
        *reinterpret_cast<uint4*>(&Bs[buf][sr][ssw]) = wv;
    };

    f32x4 acc[2][2] = {};
    prefetch(t0);
    writeLDS(0);
    __syncthreads();
    for (int tt = 0; tt < NL; ++tt) {
        if (tt + 1 < NL) prefetch(t0 + tt + 1);
        int buf = tt & 1;
        short8 a0 = *reinterpret_cast<const short8*>(&As[buf][wr + lrow][sp]);
        short8 a1 = *reinterpret_cast<const short8*>(&As[buf][wr + 16 + lrow][sp]);
        short8 bv0 = *reinterpret_cast<const short8*>(&Bs[buf][wc + lrow][sp]);
        short8 bv1 = *reinterpret_cast<const short8*>(&Bs[buf][wc + 16 + lrow][sp]);
        acc[0][0] = __builtin_amdgcn_mfma_f32_16x16x32_bf16(a0, bv0, acc[0][0], 0, 0, 0);
        acc[0][1] = __builtin_amdgcn_mfma_f32_16x16x32_bf16(a0, bv1, acc[0][1], 0, 0, 0);
        acc[1][0] = __builtin_amdgcn_mfma_f32_16x16x32_bf16(a1, bv0, acc[1][0], 0, 0, 0);
        acc[1][1] = __builtin_amdgcn_mfma_f32_16x16x32_bf16(a1, bv1, acc[1][1], 0, 0, 0);
        if (tt + 1 < NL) {
            writeLDS((tt + 1) & 1);
            __syncthreads();
        }
    }

    const float* bias = b0;
    if (MODE == 1) {
        int sel = colbase >> 8;
        bias = sel == 0 ? b0 : (sel == 1 ? b1 : b2);
    }
    int colq = (colbase & 255);
    float* Cp = (MODE == 0) ? C + (size_t)blockIdx.z * pstride : C;
    #pragma unroll
    for (int fr = 0; fr < 2; ++fr) {
        #pragma unroll
        for (int fc = 0; fc < 2; ++fc) {
            int coll = wc + fc * 16 + (lane & 15);
            int col = colbase + coll;
            #pragma unroll
            for (int i = 0; i < 4; ++i) {
                int row = rowbase + wr + fr * 16 + (lane >> 4) * 4 + i;
                float v = acc[fr][fc][i];
                if (MODE == 0) {
                    Cp[(size_t)row * ldc + col] = v;
                } else if (MODE == 1) {
                    Cp[(size_t)row * ldc + col] = v + bias[colq + coll];
                } else {
                    v += bias[col];
                    v = 0.5f * v * (1.0f + erff(v * 0.70710678118654752f));
                    Cb[(size_t)row * ldc + col] = f2b(v);
                }
            }
        }
    }
}

// ---------------------------------------------------------------- attention: one block per (b,n)
__global__ __launch_bounds__(256) void attn_kernel(const float* __restrict__ QKV,
                                                   const int* __restrict__ idx_j,
                                                   const float* __restrict__ d_ij,
                                                   const void* __restrict__ mask,
                                                   const float* __restrict__ shifts,
                                                   const float* __restrict__ Wrb,
                                                   const float* __restrict__ brb,
                                                   const int* __restrict__ flag,
                                                   unsigned short* __restrict__ Ub) {
    __shared__ float qs[Ff];
    __shared__ float rad[Mm][Rr];
    __shared__ float att[Hh][Mm];
    __shared__ float attbar[Mm];
    __shared__ int   jl[Mm];
    __shared__ float shs[Rr];

    int row = blockIdx.x;
    int b = row >> 9;
    int tid = threadIdx.x;
    bool boolmask = (*flag != 0);

    if (tid < Mm) jl[tid] = idx_j[row * Mm + tid];
    if (tid < Rr) shs[tid] = shifts[tid];
    qs[tid] = QKV[(size_t)row * 768 + tid];
    __syncthreads();

    for (int i = tid; i < Mm * Rr; i += 256) {
        int m = i >> 5, r = i & 31;
        float d = d_ij[row * Mm + m];
        float t = d - shs[r];
        rad[m][r] = expf(-4.0f * t * t);
    }
    __syncthreads();

    // scores: 512 items (m,h), float4 K loads
    for (int it = tid; it < Mm * Hh; it += 256) {
        int m = it >> 3, h = it & 7;
        int mi = row * Mm + m;
        bool msk = boolmask ? (((const unsigned char*)mask)[mi] != 0)
                            : (((const int*)mask)[mi] != 0);
        float sv;
        if (msk) {
            sv = -INFINITY;
        } else {
            int j = jl[m];
            const float4* kr4 = reinterpret_cast<const float4*>(QKV + (size_t)(b * Nn + j) * 768 + 256 + h * 32);
            const float4* q4  = reinterpret_cast<const float4*>(qs + h * 32);
            float acc = 0.f;
            #pragma unroll
            for (int c = 0; c < 8; ++c) {
                float4 kv = kr4[c], qv = q4[c];
                acc += qv.x * kv.x + qv.y * kv.y + qv.z * kv.z + qv.w * kv.w;
            }
            acc *= 0.17677669529663687f;
            const float* wr = Wrb + h * Rr;
            float accr = 0.f;
            #pragma unroll
            for (int r = 0; r < Rr; ++r) accr = fmaf(rad[m][r], wr[r], accr);
            sv = acc + accr + brb[h];
        }
        att[h][m] = sv;
    }
    __syncthreads();

    // softmax over m per head
    {
        int h = tid >> 5, l = tid & 31;
        float s0 = att[h][l], s1 = att[h][l + 32];
        float mx = fmaxf(s0, s1);
        #pragma unroll
        for (int off = 16; off; off >>= 1) mx = fmaxf(mx, __shfl_xor(mx, off, 32));
        float e0 = 0.f, e1 = 0.f;
        if (mx != -INFINITY) {
            e0 = expf(s0 - mx);
            e1 = expf(s1 - mx);
        }
        float sm = e0 + e1;
        #pragma unroll
        for (int off = 16; off; off >>= 1) sm += __shfl_xor(sm, off, 32);
        float inv = sm > 0.f ? 1.f / sm : 0.f;
        att[h][l] = e0 * inv;
        att[h][l + 32] = e1 * inv;
    }
    __syncthreads();

    if (tid < Mm) {
        float sv = 0.f;
        #pragma unroll
        for (int h = 0; h < Hh; ++h) sv += att[h][tid];
        attbar[tid] = sv * 0.125f;
    }
    __syncthreads();

    // context: 4 lanes per float4 output group, float4 V loads
    {
        int g = tid >> 2;            // 0..63
        int h = g >> 3, d4 = g & 7;
        int sub = tid & 3;
        float4 acc4 = {0.f, 0.f, 0.f, 0.f};
        for (int m = sub; m < Mm; m += 4) {
            const float4* vr = reinterpret_cast<const float4*>(
                QKV + (size_t)(b * Nn + jl[m]) * 768 + 512 + h * 32 + d4 * 4);
            float w = att[h][m];
            float4 v = *vr;
            acc4.x = fmaf(w, v.x, acc4.x);
            acc4.y = fmaf(w, v.y, acc4.y);
            acc4.z = fmaf(w, v.z, acc4.z);
            acc4.w = fmaf(w, v.w, acc4.w);
        }
        #pragma unroll
        for (int off = 1; off <= 2; off <<= 1) {
            acc4.x += __shfl_xor(acc4.x, off);
            acc4.y += __shfl_xor(acc4.y, off);
            acc4.z += __shfl_xor(acc4.z, off);
            acc4.w += __shfl_xor(acc4.w, off);
        }
        if (sub == 0) {
            ushort4 u;
            u.x = f2b(acc4.x); u.y = f2b(acc4.y); u.z = f2b(acc4.z); u.w = f2b(acc4.w);
            *reinterpret_cast<ushort4*>(&Ub[(size_t)row * KOUT + Ff + g * 4]) = u;
        }
    }
    // radial context
    if (tid < Rr) {
        float acc = 0.f;
        for (int m = 0; m < Mm; ++m) acc = fmaf(attbar[m], rad[m][tid], acc);
        Ub[(size_t)row * KOUT + 2 * Ff + tid] = f2b(acc);
    }
}

// ---------------------------------------------------------------- residual + bias + S partials + LN (wave per row)
template<int S, int WB>
__global__ __launch_bounds__(256) void add_ln_c(const float* __restrict__ x0,
                                                const float* __restrict__ part, size_t pstride,
                                                const float* __restrict__ bias,
                                                const float* __restrict__ g,
                                                const float* __restrict__ be,
                                                float* __restrict__ outp,
                                                unsigned short* __restrict__ xb) {
    int tid = threadIdx.x;
    int wave = tid >> 6, lane = tid & 63;
    int row = blockIdx.x * 4 + wave;
    size_t off = (size_t)row * Ff + lane * 4;
    float4 v = *reinterpret_cast<const float4*>(x0 + off);
    float4 bb = *reinterpret_cast<const float4*>(bias + lane * 4);
    v.x += bb.x; v.y += bb.y; v.z += bb.z; v.w += bb.w;
    #pragma unroll
    for (int s = 0; s < S; ++s) {
        float4 p = *reinterpret_cast<const float4*>(part + (size_t)s * pstride + off);
        v.x += p.x; v.y += p.y; v.z += p.z; v.w += p.w;
    }
    float sm = v.x + v.y + v.z + v.w;
    #pragma unroll
    for (int o = 32; o; o >>= 1) sm += __shfl_xor(sm, o, 64);
    float mu = sm * (1.f / Ff);
    float4 c = {v.x - mu, v.y - mu, v.z - mu, v.w - mu};
    float s2 = c.x * c.x + c.y * c.y + c.z * c.z + c.w * c.w;
    #pragma unroll
    for (int o = 32; o; o >>= 1) s2 += __shfl_xor(s2, o, 64);
    float inv = rsqrtf(s2 * (1.f / Ff) + 1e-5f);
    float4 gg = *reinterpret_cast<const float4*>(g + lane * 4);
    float4 ee = *reinterpret_cast<const float4*>(be + lane * 4);
    float4 r;
    r.x = c.x * inv * gg.x + ee.x;
    r.y = c.y * inv * gg.y + ee.y;
    r.z = c.z * inv * gg.z + ee.z;
    r.w = c.w * inv * gg.w + ee.w;
    *reinterpret_cast<float4*>(outp + off) = r;
    if (WB) {
        ushort4 u;
        u.x = f2b(r.x); u.y = f2b(r.y); u.z = f2b(r.z); u.w = f2b(r.w);
        *reinterpret_cast<ushort4*>(&xb[off]) = u;
    }
}

// ---------------------------------------------------------------- launch
extern "C" void kernel_launch(void* const* d_in, const int* in_sizes, int n_in,
                              void* d_out, int out_size, void* d_ws, size_t ws_size,
                              hipStream_t stream) {
    const float* a       = (const float*)d_in[0];
    const float* charges = (const float*)d_in[1];
    const int*   idx_j   = (const int*)  d_in[2];
    const float* d_ij    = (const float*)d_in[3];
    const void*  mask    =               d_in[4];
    const float* shifts  = (const float*)d_in[5];
    const float* Wq   = (const float*)d_in[6];  const float* bq   = (const float*)d_in[7];
    const float* Wk   = (const float*)d_in[8];  const float* bk   = (const float*)d_in[9];
    const float* Wv   = (const float*)d_in[10]; const float* bv   = (const float*)d_in[11];
    const float* Wrb  = (const float*)d_in[12]; const float* brb  = (const float*)d_in[13];
    const float* Wout = (const float*)d_in[14]; const float* bout = (const float*)d_in[15];
    const float* g1   = (const float*)d_in[16]; const float* b1   = (const float*)d_in[17];
    const float* g2   = (const float*)d_in[18]; const float* b2   = (const float*)d_in[19];
    const float* Wf1  = (const float*)d_in[20]; const float* bf1  = (const float*)d_in[21];
    const float* Wf2  = (const float*)d_in[22]; const float* bf2  = (const float*)d_in[23];
    float* outp = (float*)d_out;

    float* ws   = (float*)d_ws;
    int*   flag = (int*)d_ws;
    // ws layout (floats): flag(1024) | QKVb/part slot (2,097,152) | xbuf (524,288) | bf16 arena
    float* QKVb = ws + 1024;                       // [2048 x 768] fp32 (dead after attn)
    float* part = QKVb;                            // split-K partials reuse the slot
    float* xbuf = QKVb + 2097152;                  // [2048 x 256] fp32
    unsigned short* arena = (unsigned short*)(xbuf + (size_t)ROWS * Ff);
    unsigned short* centerb = arena + OFF_CENTER;
    unsigned short* Wqkvb   = arena + OFF_WQKV;
    unsigned short* Woutb   = arena + OFF_WOUT;
    unsigned short* Wf1b    = arena + OFF_WF1;
    unsigned short* Wf2b    = arena + OFF_WF2;
    unsigned short* Ub      = arena + OFF_U;
    unsigned short* xb      = arena + OFF_XB;
    unsigned short* ffhb    = arena + OFF_FFH;

    hipMemsetAsync(flag, 0, sizeof(int), stream);
    prep<<<CONV_BLK + A2U_BLK + MSK_BLK, 256, 0, stream>>>(
        a, charges, Wq, Wk, Wv, Wout, Wf1, Wf2, (const unsigned char*)mask, flag, arena);

    // QKV: [2048 x 768], K=288 (9 tiles), bias fused
    gemm_mfma<9, 1, 1><<<dim3(12, 32, 1), 256, 0, stream>>>(
        centerb, KINP, Wqkvb, KINP, bq, bk, bv, QKVb, nullptr, 768, 0);

    attn_kernel<<<ROWS, 256, 0, stream>>>(QKVb, idx_j, d_ij, mask, shifts, Wrb, brb, flag, Ub);

    // Wout: [2048 x 256], K=544 (17 tiles), split 2
    gemm_mfma<17, 2, 0><<<dim3(4, 32, 2), 256, 0, stream>>>(
        Ub, KOUT, Woutb, KOUT, nullptr, nullptr, nullptr, part, nullptr, Ff, (size_t)ROWS * Ff);
    add_ln_c<2, 1><<<ROWS / 4, 256, 0, stream>>>(a, part, (size_t)ROWS * Ff, bout, g1, b1, xbuf, xb);

    // FFN1: [2048 x 512], K=256 (8 tiles), GELU+bias epilogue -> bf16
    gemm_mfma<8, 1, 2><<<dim3(8, 32, 1), 256, 0, stream>>>(
        xb, Ff, Wf1b, Ff, bf1, nullptr, nullptr, nullptr, ffhb, FFNH, 0);

    // FFN2: [2048 x 256], K=512 (16 tiles), split 2
    gemm_mfma<16, 2, 0><<<dim3(4, 32, 2), 256, 0, stream>>>(
        ffhb, FFNH, Wf2b, FFNH, nullptr, nullptr, nullptr, part, nullptr, Ff, (size_t)ROWS * Ff);
    add_ln_c<2, 0><<<ROWS / 4, 256, 0, stream>>>(xbuf, part, (size_t)ROWS * Ff, bf2, g2, b2, outp, nullptr);
}

// Round 6
// 73.931 us; speedup vs baseline: 6.8951x; 1.2553x over previous
//
#include <hip/hip_runtime.h>
#include <hip/hip_bf16.h>
#include <math.h>

// Problem constants
#define Bb 4
#define Nn 512
#define Mm 64
#define Ff 256
#define Qq 16
#define Hh 8
#define Rr 32
#define FFNH 512
#define ROWS (Bb*Nn)          // 2048
#define KIN (Ff+Qq)           // 272
#define KINP 288              // padded to 9*32
#define KOUT (2*Ff+Rr)        // 544 = 17*32

typedef short short8 __attribute__((ext_vector_type(8)));
typedef float f32x4 __attribute__((ext_vector_type(4)));

__device__ inline unsigned short f2b(float f) {
    union { float f; unsigned u; } c; c.f = f;
    unsigned r = c.u + 0x7fffu + ((c.u >> 16) & 1u);
    return (unsigned short)(r >> 16);
}

// arena segments (ushort offsets)
#define OFF_CENTER 0
#define OFF_WQKV   (OFF_CENTER + ROWS*KINP)            // 589824
#define OFF_WOUT   (OFF_WQKV + 768*KINP)               // 811008
#define OFF_WF1    (OFF_WOUT + Ff*KOUT)                // 950272
#define OFF_WF2    (OFF_WF1 + FFNH*Ff)                 // 1081344
#define OFF_U      (OFF_WF2 + Ff*FFNH)                 // 1212416
#define OFF_XB     (OFF_U + ROWS*KOUT)                 // 2326528
#define OFF_FFH    (OFF_XB + ROWS*Ff)                  // 2850816
#define CONV_TOTAL OFF_U                               // 1212416
#define CONV_BLK   (CONV_TOTAL/256)                    // 4736
#define A2U_BLK    (ROWS*Ff/256)                       // 2048
#define MSK_BLK    (Bb*Nn*Mm/256)                      // 512

// ---------------------------------------------------------------- prep: convert + U[:, :256]=bf16(a) + detect mask
__global__ __launch_bounds__(256) void prep(const float* __restrict__ a,
                                            const float* __restrict__ ch,
                                            const float* __restrict__ Wq,
                                            const float* __restrict__ Wk,
                                            const float* __restrict__ Wv,
                                            const float* __restrict__ Wout,
                                            const float* __restrict__ Wf1,
                                            const float* __restrict__ Wf2,
                                            const unsigned char* __restrict__ mask,
                                            int* __restrict__ flag,
                                            unsigned short* __restrict__ arena) {
    int bid = blockIdx.x, tid = threadIdx.x;
    if (bid < CONV_BLK) {
        int i = bid * 256 + tid;
        float v;
        if (i < OFF_WQKV) {
            int row = i / KINP, c = i - row * KINP;
            v = (c < Ff) ? a[(size_t)row * Ff + c] : (c < KIN ? ch[(size_t)row * Qq + (c - Ff)] : 0.f);
        } else if (i < OFF_WOUT) {
            int j = i - OFF_WQKV;
            int n = j / KINP, c = j - n * KINP;
            const float* W = n < 256 ? Wq : (n < 512 ? Wk : Wv);
            int nr = n & 255;
            v = (c < KIN) ? W[(size_t)nr * KIN + c] : 0.f;
        } else if (i < OFF_WF1) {
            v = Wout[i - OFF_WOUT];
        } else if (i < OFF_WF2) {
            v = Wf1[i - OFF_WF1];
        } else {
            v = Wf2[i - OFF_WF2];
        }
        arena[i] = f2b(v);
    } else if (bid < CONV_BLK + A2U_BLK) {
        int j = (bid - CONV_BLK) * 256 + tid;
        int row = j >> 8, col = j & 255;
        arena[OFF_U + (size_t)row * KOUT + col] = f2b(a[j]);
    } else {
        int i = (bid - CONV_BLK - A2U_BLK) * 256 + tid;
        if ((i & 3) && mask[i]) *flag = 1;
    }
}

// ---------------------------------------------------------------- MFMA GEMM: C = A(bf16) @ W(bf16)^T
// MODE 0: fp32 out (split-K partials via blockIdx.z, no bias)
// MODE 1: fp32 out + bias selected from b0/b1/b2 per 256-col block (QKV)
// MODE 2: bias b0 + exact GELU -> bf16 out Cb
template<int KT, int SPLIT, int MODE>
__global__ __launch_bounds__(256) void gemm_mfma(const unsigned short* __restrict__ Ab, int lda,
                                                 const unsigned short* __restrict__ Wb, int ldw,
                                                 const float* __restrict__ b0,
                                                 const float* __restrict__ b1,
                                                 const float* __restrict__ b2,
                                                 float* __restrict__ C,
                                                 unsigned short* __restrict__ Cb,
                                                 int ldc, size_t pstride) {
    __shared__ unsigned short As[2][64][32];
    __shared__ unsigned short Bs[2][64][32];
    int tid = threadIdx.x;
    int colbase = blockIdx.x * 64;
    int rowbase = blockIdx.y * 64;
    constexpr int TPER = (KT + SPLIT - 1) / SPLIT;
    int t0 = blockIdx.z * TPER;
    int NL = KT - t0; if (NL > TPER) NL = TPER;

    int sr = tid >> 2, sl = tid & 3;
    const unsigned short* Ap = Ab + (size_t)(rowbase + sr) * lda + sl * 8;
    const unsigned short* Wp = Wb + (size_t)(colbase + sr) * ldw + sl * 8;
    int ssw = (sl ^ (sr & 3)) * 8;

    int wave = tid >> 6, lane = tid & 63;
    int wr = (wave >> 1) * 32, wc = (wave & 1) * 32;
    int lrow = lane & 15;
    int kslot = lane >> 4;
    int sp = (kslot ^ (lane & 3)) * 8;

    uint4 av, wv;
    auto prefetch = [&](int t) {
        av = *reinterpret_cast<const uint4*>(Ap + (size_t)t * 32);
        wv = *reinterpret_cast<const uint4*>(Wp + (size_t)t * 32);
    };
    auto writeLDS = [&](int buf) {
        *reinterpret_cast<uint4*>(&As[buf][sr][ssw]) = av;
        *reinterpret_cast<uint4*>(&Bs[buf][sr][ssw]) = wv;
    };

    f32x4 acc[2][2] = {};
    prefetch(t0);
    writeLDS(0);
    __syncthreads();
    for (int tt = 0; tt < NL; ++tt) {
        if (tt + 1 < NL) prefetch(t0 + tt + 1);
        int buf = tt & 1;
        short8 a0 = *reinterpret_cast<const short8*>(&As[buf][wr + lrow][sp]);
        short8 a1 = *reinterpret_cast<const short8*>(&As[buf][wr + 16 + lrow][sp]);
        short8 bv0 = *reinterpret_cast<const short8*>(&Bs[buf][wc + lrow][sp]);
        short8 bv1 = *reinterpret_cast<const short8*>(&Bs[buf][wc + 16 + lrow][sp]);
        acc[0][0] = __builtin_amdgcn_mfma_f32_16x16x32_bf16(a0, bv0, acc[0][0], 0, 0, 0);
        acc[0][1] = __builtin_amdgcn_mfma_f32_16x16x32_bf16(a0, bv1, acc[0][1], 0, 0, 0);
        acc[1][0] = __builtin_amdgcn_mfma_f32_16x16x32_bf16(a1, bv0, acc[1][0], 0, 0, 0);
        acc[1][1] = __builtin_amdgcn_mfma_f32_16x16x32_bf16(a1, bv1, acc[1][1], 0, 0, 0);
        if (tt + 1 < NL) {
            writeLDS((tt + 1) & 1);
            __syncthreads();
        }
    }

    const float* bias = b0;
    if (MODE == 1) {
        int sel = colbase >> 8;
        bias = sel == 0 ? b0 : (sel == 1 ? b1 : b2);
    }
    int colq = (colbase & 255);
    float* Cp = (MODE == 0) ? C + (size_t)blockIdx.z * pstride : C;
    #pragma unroll
    for (int fr = 0; fr < 2; ++fr) {
        #pragma unroll
        for (int fc = 0; fc < 2; ++fc) {
            int coll = wc + fc * 16 + (lane & 15);
            int col = colbase + coll;
            #pragma unroll
            for (int i = 0; i < 4; ++i) {
                int row = rowbase + wr + fr * 16 + (lane >> 4) * 4 + i;
                float v = acc[fr][fc][i];
                if (MODE == 0) {
                    Cp[(size_t)row * ldc + col] = v;
                } else if (MODE == 1) {
                    Cp[(size_t)row * ldc + col] = v + bias[colq + coll];
                } else {
                    v += bias[col];
                    v = 0.5f * v * (1.0f + erff(v * 0.70710678118654752f));
                    Cb[(size_t)row * ldc + col] = f2b(v);
                }
            }
        }
    }
}

// ---------------------------------------------------------------- attention v2: LDS-staged K/V tiles
// one block per (b,n); K/V gathered rows staged coalesced into LDS in 16-row tiles.
__global__ __launch_bounds__(256) void attn_kernel(const float* __restrict__ QKV,
                                                   const int* __restrict__ idx_j,
                                                   const float* __restrict__ d_ij,
                                                   const void* __restrict__ mask,
                                                   const float* __restrict__ shifts,
                                                   const float* __restrict__ Wrb,
                                                   const float* __restrict__ brb,
                                                   const int* __restrict__ flag,
                                                   unsigned short* __restrict__ Ub) {
    __shared__ float Ktile[16][260];   // 16.6 KB, staged K rows then V rows
    __shared__ float rad[Mm][36];      // 9.2 KB
    __shared__ float att[Hh][Mm];      // 2 KB
    __shared__ float attbar[Mm];
    __shared__ int   jl[Mm];
    __shared__ float dv[Mm];
    __shared__ int   maskf[Mm];
    __shared__ float shs[Rr];

    int row = blockIdx.x;
    int b = row >> 9;                  // N=512
    int tid = threadIdx.x;
    bool boolmask = (*flag != 0);

    // prologue small loads (disjoint thread ranges)
    if (tid < Mm) jl[tid] = idx_j[row * Mm + tid];
    else if (tid < 128) { int m = tid - 64; dv[m] = d_ij[row * Mm + m]; }
    else if (tid < 160) shs[tid - 128] = shifts[tid - 128];
    else if (tid >= 192) {
        int m = tid - 192;
        maskf[m] = boolmask ? (int)((const unsigned char*)mask)[row * Mm + m]
                            : ((const int*)mask)[row * Mm + m];
    }

    // per-thread registers for score role: pair p = tid>>1; item (m = p&15 per tile, h = p>>4)
    int half = tid & 1;
    int p = tid >> 1;
    int hh = p >> 4;          // 0..7
    int ml = p & 15;          // 0..15
    float4 qreg[4], wreg[4];
    #pragma unroll
    for (int c = 0; c < 4; ++c) {
        qreg[c] = *reinterpret_cast<const float4*>(QKV + (size_t)row * 768 + hh * 32 + half * 16 + c * 4);
        wreg[c] = *reinterpret_cast<const float4*>(Wrb + hh * Rr + half * 16 + c * 4);
    }
    float brbh = brb[hh];
    __syncthreads();

    // coalesced gather-stage of 16 rows (seg: 256=K, 512=V)
    int sw = tid >> 6, sl = tid & 63;
    int rloc = sw * 4 + (sl >> 4);
    int scol = sl & 15;
    auto stage = [&](int t, int seg) {
        int j = jl[t * 16 + rloc];
        const float4* src = reinterpret_cast<const float4*>(QKV + (size_t)(b * Nn + j) * 768 + seg);
        #pragma unroll
        for (int c = 0; c < 4; ++c) {
            float4 v = src[c * 16 + scol];
            *reinterpret_cast<float4*>(&Ktile[rloc][c * 64 + scol * 4]) = v;
        }
    };

    // radial basis into rad + stage K tile 0
    #pragma unroll
    for (int it = 0; it < 8; ++it) {
        int i = tid + it * 256;
        int m = i >> 5, r = i & 31;
        float t = dv[m] - shs[r];
        rad[m][r] = expf(-4.0f * t * t);
    }
    stage(0, 256);
    __syncthreads();

    // pass 1: scores per 16-row tile
    for (int t = 0; t < 4; ++t) {
        float accK = 0.f, accR = 0.f;
        #pragma unroll
        for (int c = 0; c < 4; ++c) {
            float4 kv = *reinterpret_cast<const float4*>(&Ktile[ml][hh * 32 + half * 16 + c * 4]);
            accK += qreg[c].x * kv.x + qreg[c].y * kv.y + qreg[c].z * kv.z + qreg[c].w * kv.w;
            float4 rv = *reinterpret_cast<const float4*>(&rad[t * 16 + ml][half * 16 + c * 4]);
            accR += wreg[c].x * rv.x + wreg[c].y * rv.y + wreg[c].z * rv.z + wreg[c].w * rv.w;
        }
        float tv = accK * 0.17677669529663687f + accR;
        tv += __shfl_xor(tv, 1);
        if (!half) {
            int m = t * 16 + ml;
            att[hh][m] = maskf[m] ? -INFINITY : (tv + brbh);
        }
        __syncthreads();
        if (t < 3) { stage(t + 1, 256); __syncthreads(); }
    }

    // softmax over m per head
    {
        int h = tid >> 5, l = tid & 31;
        float s0 = att[h][l], s1 = att[h][l + 32];
        float mx = fmaxf(s0, s1);
        #pragma unroll
        for (int off = 16; off; off >>= 1) mx = fmaxf(mx, __shfl_xor(mx, off, 32));
        float e0 = 0.f, e1 = 0.f;
        if (mx != -INFINITY) {
            e0 = expf(s0 - mx);
            e1 = expf(s1 - mx);
        }
        float sm = e0 + e1;
        #pragma unroll
        for (int off = 16; off; off >>= 1) sm += __shfl_xor(sm, off, 32);
        float inv = sm > 0.f ? 1.f / sm : 0.f;
        att[h][l] = e0 * inv;
        att[h][l + 32] = e1 * inv;
    }
    __syncthreads();

    // attbar + stage V tile 0
    if (tid < Mm) {
        float sv = 0.f;
        #pragma unroll
        for (int h = 0; h < Hh; ++h) sv += att[h][tid];
        attbar[tid] = sv * 0.125f;
    }
    stage(0, 512);
    __syncthreads();

    // pass 2: context accumulation per tile
    float ctx = 0.f;
    int h2 = tid >> 5, d0 = tid & 31;
    for (int t = 0; t < 4; ++t) {
        #pragma unroll
        for (int m = 0; m < 16; ++m)
            ctx = fmaf(att[h2][t * 16 + m], Ktile[m][h2 * 32 + d0], ctx);
        __syncthreads();
        if (t < 3) { stage(t + 1, 512); __syncthreads(); }
    }

    // write context
    Ub[(size_t)row * KOUT + Ff + tid] = f2b(ctx);

    // radial context: pair-split over m
    if (tid < 64) {
        int g = tid >> 1;
        float acc = 0.f;
        #pragma unroll
        for (int i = 0; i < 32; ++i) {
            int m = half * 32 + i;
            acc = fmaf(attbar[m], rad[m][g], acc);
        }
        acc += __shfl_xor(acc, 1);
        if (!half) Ub[(size_t)row * KOUT + 2 * Ff + g] = f2b(acc);
    }
}

// ---------------------------------------------------------------- residual + bias + S partials + LN (wave per row)
template<int S, int WB>
__global__ __launch_bounds__(256) void add_ln_c(const float* __restrict__ x0,
                                                const float* __restrict__ part, size_t pstride,
                                                const float* __restrict__ bias,
                                                const float* __restrict__ g,
                                                const float* __restrict__ be,
                                                float* __restrict__ outp,
                                                unsigned short* __restrict__ xb) {
    int tid = threadIdx.x;
    int wave = tid >> 6, lane = tid & 63;
    int row = blockIdx.x * 4 + wave;
    size_t off = (size_t)row * Ff + lane * 4;
    float4 v = *reinterpret_cast<const float4*>(x0 + off);
    float4 bb = *reinterpret_cast<const float4*>(bias + lane * 4);
    v.x += bb.x; v.y += bb.y; v.z += bb.z; v.w += bb.w;
    #pragma unroll
    for (int s = 0; s < S; ++s) {
        float4 p = *reinterpret_cast<const float4*>(part + (size_t)s * pstride + off);
        v.x += p.x; v.y += p.y; v.z += p.z; v.w += p.w;
    }
    float sm = v.x + v.y + v.z + v.w;
    #pragma unroll
    for (int o = 32; o; o >>= 1) sm += __shfl_xor(sm, o, 64);
    float mu = sm * (1.f / Ff);
    float4 c = {v.x - mu, v.y - mu, v.z - mu, v.w - mu};
    float s2 = c.x * c.x + c.y * c.y + c.z * c.z + c.w * c.w;
    #pragma unroll
    for (int o = 32; o; o >>= 1) s2 += __shfl_xor(s2, o, 64);
    float inv = rsqrtf(s2 * (1.f / Ff) + 1e-5f);
    float4 gg = *reinterpret_cast<const float4*>(g + lane * 4);
    float4 ee = *reinterpret_cast<const float4*>(be + lane * 4);
    float4 r;
    r.x = c.x * inv * gg.x + ee.x;
    r.y = c.y * inv * gg.y + ee.y;
    r.z = c.z * inv * gg.z + ee.z;
    r.w = c.w * inv * gg.w + ee.w;
    *reinterpret_cast<float4*>(outp + off) = r;
    if (WB) {
        ushort4 u;
        u.x = f2b(r.x); u.y = f2b(r.y); u.z = f2b(r.z); u.w = f2b(r.w);
        *reinterpret_cast<ushort4*>(&xb[off]) = u;
    }
}

// ---------------------------------------------------------------- launch
extern "C" void kernel_launch(void* const* d_in, const int* in_sizes, int n_in,
                              void* d_out, int out_size, void* d_ws, size_t ws_size,
                              hipStream_t stream) {
    const float* a       = (const float*)d_in[0];
    const float* charges = (const float*)d_in[1];
    const int*   idx_j   = (const int*)  d_in[2];
    const float* d_ij    = (const float*)d_in[3];
    const void*  mask    =               d_in[4];
    const float* shifts  = (const float*)d_in[5];
    const float* Wq   = (const float*)d_in[6];  const float* bq   = (const float*)d_in[7];
    const float* Wk   = (const float*)d_in[8];  const float* bk   = (const float*)d_in[9];
    const float* Wv   = (const float*)d_in[10]; const float* bv   = (const float*)d_in[11];
    const float* Wrb  = (const float*)d_in[12]; const float* brb  = (const float*)d_in[13];
    const float* Wout = (const float*)d_in[14]; const float* bout = (const float*)d_in[15];
    const float* g1   = (const float*)d_in[16]; const float* b1   = (const float*)d_in[17];
    const float* g2   = (const float*)d_in[18]; const float* b2   = (const float*)d_in[19];
    const float* Wf1  = (const float*)d_in[20]; const float* bf1  = (const float*)d_in[21];
    const float* Wf2  = (const float*)d_in[22]; const float* bf2  = (const float*)d_in[23];
    float* outp = (float*)d_out;

    float* ws   = (float*)d_ws;
    int*   flag = (int*)d_ws;
    // ws layout (floats): flag(1024) | QKVb/part slot (2,097,152) | xbuf (524,288) | bf16 arena
    float* QKVb = ws + 1024;                       // [2048 x 768] fp32 (dead after attn)
    float* part = QKVb;                            // split-K partials reuse the slot
    float* xbuf = QKVb + 2097152;                  // [2048 x 256] fp32
    unsigned short* arena = (unsigned short*)(xbuf + (size_t)ROWS * Ff);
    unsigned short* centerb = arena + OFF_CENTER;
    unsigned short* Wqkvb   = arena + OFF_WQKV;
    unsigned short* Woutb   = arena + OFF_WOUT;
    unsigned short* Wf1b    = arena + OFF_WF1;
    unsigned short* Wf2b    = arena + OFF_WF2;
    unsigned short* Ub      = arena + OFF_U;
    unsigned short* xb      = arena + OFF_XB;
    unsigned short* ffhb    = arena + OFF_FFH;

    hipMemsetAsync(flag, 0, sizeof(int), stream);
    prep<<<CONV_BLK + A2U_BLK + MSK_BLK, 256, 0, stream>>>(
        a, charges, Wq, Wk, Wv, Wout, Wf1, Wf2, (const unsigned char*)mask, flag, arena);

    // QKV: [2048 x 768], K=288 (9 tiles), bias fused
    gemm_mfma<9, 1, 1><<<dim3(12, 32, 1), 256, 0, stream>>>(
        centerb, KINP, Wqkvb, KINP, bq, bk, bv, QKVb, nullptr, 768, 0);

    attn_kernel<<<ROWS, 256, 0, stream>>>(QKVb, idx_j, d_ij, mask, shifts, Wrb, brb, flag, Ub);

    // Wout: [2048 x 256], K=544 (17 tiles), split 2
    gemm_mfma<17, 2, 0><<<dim3(4, 32, 2), 256, 0, stream>>>(
        Ub, KOUT, Woutb, KOUT, nullptr, nullptr, nullptr, part, nullptr, Ff, (size_t)ROWS * Ff);
    add_ln_c<2, 1><<<ROWS / 4, 256, 0, stream>>>(a, part, (size_t)ROWS * Ff, bout, g1, b1, xbuf, xb);

    // FFN1: [2048 x 512], K=256 (8 tiles), GELU+bias epilogue -> bf16
    gemm_mfma<8, 1, 2><<<dim3(8, 32, 1), 256, 0, stream>>>(
        xb, Ff, Wf1b, Ff, bf1, nullptr, nullptr, nullptr, ffhb, FFNH, 0);

    // FFN2: [2048 x 256], K=512 (16 tiles), split 2
    gemm_mfma<16, 2, 0><<<dim3(4, 32, 2), 256, 0, stream>>>(
        ffhb, FFNH, Wf2b, FFNH, nullptr, nullptr, nullptr, part, nullptr, Ff, (size_t)ROWS * Ff);
    add_ln_c<2, 0><<<ROWS / 4, 256, 0, stream>>>(xbuf, part, (size_t)ROWS * Ff, bf2, g2, b2, outp, nullptr);
}

// Round 7
// 65.642 us; speedup vs baseline: 7.7658x; 1.1263x over previous
//
#include <hip/hip_runtime.h>
#include <hip/hip_bf16.h>
#include <math.h>

// Problem constants
#define Bb 4
#define Nn 512
#define Mm 64
#define Ff 256
#define Qq 16
#define Hh 8
#define Rr 32
#define FFNH 512
#define ROWS (Bb*Nn)          // 2048
#define KIN (Ff+Qq)           // 272
#define KINP 288              // padded to 9*32
#define KOUT (2*Ff+Rr)        // 544 = 17*32

typedef short short8 __attribute__((ext_vector_type(8)));
typedef unsigned short ushort8 __attribute__((ext_vector_type(8)));
typedef float f32x4 __attribute__((ext_vector_type(4)));

__device__ inline unsigned short f2b(float f) {
    union { float f; unsigned u; } c; c.f = f;
    unsigned r = c.u + 0x7fffu + ((c.u >> 16) & 1u);
    return (unsigned short)(r >> 16);
}
__device__ inline float b2f(unsigned short u) {
    union { unsigned u; float f; } c; c.u = ((unsigned)u) << 16;
    return c.f;
}

// arena segments (ushort offsets)
#define OFF_CENTER 0
#define OFF_WQKV   (OFF_CENTER + ROWS*KINP)            // 589824
#define OFF_WOUT   (OFF_WQKV + 768*KINP)               // 811008
#define OFF_WF1    (OFF_WOUT + Ff*KOUT)                // 950272
#define OFF_WF2    (OFF_WF1 + FFNH*Ff)                 // 1081344
#define OFF_U      (OFF_WF2 + Ff*FFNH)                 // 1212416
#define OFF_XB     (OFF_U + ROWS*KOUT)                 // 2326528
#define OFF_FFH    (OFF_XB + ROWS*Ff)                  // 2850816
#define OFF_QKVB   (OFF_FFH + ROWS*FFNH)               // 3899392
#define CONV_TOTAL OFF_U                               // 1212416
#define CONV_BLK   (CONV_TOTAL/256)                    // 4736
#define A2U_BLK    (ROWS*Ff/256)                       // 2048
#define MSK_BLK    (Bb*Nn*Mm/256)                      // 512

// ---------------------------------------------------------------- prep: convert + U[:, :256]=bf16(a) + detect mask
__global__ __launch_bounds__(256) void prep(const float* __restrict__ a,
                                            const float* __restrict__ ch,
                                            const float* __restrict__ Wq,
                                            const float* __restrict__ Wk,
                                            const float* __restrict__ Wv,
                                            const float* __restrict__ Wout,
                                            const float* __restrict__ Wf1,
                                            const float* __restrict__ Wf2,
                                            const unsigned char* __restrict__ mask,
                                            int* __restrict__ flag,
                                            unsigned short* __restrict__ arena) {
    int bid = blockIdx.x, tid = threadIdx.x;
    if (bid < CONV_BLK) {
        int i = bid * 256 + tid;
        float v;
        if (i < OFF_WQKV) {
            int row = i / KINP, c = i - row * KINP;
            v = (c < Ff) ? a[(size_t)row * Ff + c] : (c < KIN ? ch[(size_t)row * Qq + (c - Ff)] : 0.f);
        } else if (i < OFF_WOUT) {
            int j = i - OFF_WQKV;
            int n = j / KINP, c = j - n * KINP;
            const float* W = n < 256 ? Wq : (n < 512 ? Wk : Wv);
            int nr = n & 255;
            v = (c < KIN) ? W[(size_t)nr * KIN + c] : 0.f;
        } else if (i < OFF_WF1) {
            v = Wout[i - OFF_WOUT];
        } else if (i < OFF_WF2) {
            v = Wf1[i - OFF_WF1];
        } else {
            v = Wf2[i - OFF_WF2];
        }
        arena[i] = f2b(v);
    } else if (bid < CONV_BLK + A2U_BLK) {
        int j = (bid - CONV_BLK) * 256 + tid;
        int row = j >> 8, col = j & 255;
        arena[OFF_U + (size_t)row * KOUT + col] = f2b(a[j]);
    } else {
        int i = (bid - CONV_BLK - A2U_BLK) * 256 + tid;
        if ((i & 3) && mask[i]) *flag = 1;
    }
}

// ---------------------------------------------------------------- MFMA GEMM: C = A(bf16) @ W(bf16)^T
// MODE 0: fp32 out (split-K partials via blockIdx.z, no bias)
// MODE 1: bias per 256-col block -> bf16 out Cb (QKV)
// MODE 2: bias b0 + exact GELU -> bf16 out Cb
template<int KT, int SPLIT, int MODE>
__global__ __launch_bounds__(256) void gemm_mfma(const unsigned short* __restrict__ Ab, int lda,
                                                 const unsigned short* __restrict__ Wb, int ldw,
                                                 const float* __restrict__ b0,
                                                 const float* __restrict__ b1,
                                                 const float* __restrict__ b2,
                                                 float* __restrict__ C,
                                                 unsigned short* __restrict__ Cb,
                                                 int ldc, size_t pstride) {
    __shared__ unsigned short As[2][64][32];
    __shared__ unsigned short Bs[2][64][32];
    int tid = threadIdx.x;
    int colbase = blockIdx.x * 64;
    int rowbase = blockIdx.y * 64;
    constexpr int TPER = (KT + SPLIT - 1) / SPLIT;
    int t0 = blockIdx.z * TPER;
    int NL = KT - t0; if (NL > TPER) NL = TPER;

    int sr = tid >> 2, sl = tid & 3;
    const unsigned short* Ap = Ab + (size_t)(rowbase + sr) * lda + sl * 8;
    const unsigned short* Wp = Wb + (size_t)(colbase + sr) * ldw + sl * 8;
    int ssw = (sl ^ (sr & 3)) * 8;

    int wave = tid >> 6, lane = tid & 63;
    int wr = (wave >> 1) * 32, wc = (wave & 1) * 32;
    int lrow = lane & 15;
    int kslot = lane >> 4;
    int sp = (kslot ^ (lane & 3)) * 8;

    uint4 av, wv;
    auto prefetch = [&](int t) {
        av = *reinterpret_cast<const uint4*>(Ap + (size_t)t * 32);
        wv = *reinterpret_cast<const uint4*>(Wp + (size_t)t * 32);
    };
    auto writeLDS = [&](int buf) {
        *reinterpret_cast<uint4*>(&As[buf][sr][ssw]) = av;
        *reinterpret_cast<uint4*>(&Bs[buf][sr][ssw]) = wv;
    };

    f32x4 acc[2][2] = {};
    prefetch(t0);
    writeLDS(0);
    __syncthreads();
    for (int tt = 0; tt < NL; ++tt) {
        if (tt + 1 < NL) prefetch(t0 + tt + 1);
        int buf = tt & 1;
        short8 a0 = *reinterpret_cast<const short8*>(&As[buf][wr + lrow][sp]);
        short8 a1 = *reinterpret_cast<const short8*>(&As[buf][wr + 16 + lrow][sp]);
        short8 bv0 = *reinterpret_cast<const short8*>(&Bs[buf][wc + lrow][sp]);
        short8 bv1 = *reinterpret_cast<const short8*>(&Bs[buf][wc + 16 + lrow][sp]);
        acc[0][0] = __builtin_amdgcn_mfma_f32_16x16x32_bf16(a0, bv0, acc[0][0], 0, 0, 0);
        acc[0][1] = __builtin_amdgcn_mfma_f32_16x16x32_bf16(a0, bv1, acc[0][1], 0, 0, 0);
        acc[1][0] = __builtin_amdgcn_mfma_f32_16x16x32_bf16(a1, bv0, acc[1][0], 0, 0, 0);
        acc[1][1] = __builtin_amdgcn_mfma_f32_16x16x32_bf16(a1, bv1, acc[1][1], 0, 0, 0);
        if (tt + 1 < NL) {
            writeLDS((tt + 1) & 1);
            __syncthreads();
        }
    }

    const float* bias = b0;
    if (MODE == 1) {
        int sel = colbase >> 8;
        bias = sel == 0 ? b0 : (sel == 1 ? b1 : b2);
    }
    int colq = (colbase & 255);
    float* Cp = (MODE == 0) ? C + (size_t)blockIdx.z * pstride : C;
    #pragma unroll
    for (int fr = 0; fr < 2; ++fr) {
        #pragma unroll
        for (int fc = 0; fc < 2; ++fc) {
            int coll = wc + fc * 16 + (lane & 15);
            int col = colbase + coll;
            #pragma unroll
            for (int i = 0; i < 4; ++i) {
                int row = rowbase + wr + fr * 16 + (lane >> 4) * 4 + i;
                float v = acc[fr][fc][i];
                if (MODE == 0) {
                    Cp[(size_t)row * ldc + col] = v;
                } else if (MODE == 1) {
                    Cb[(size_t)row * ldc + col] = f2b(v + bias[colq + coll]);
                } else {
                    v += bias[col];
                    v = 0.5f * v * (1.0f + erff(v * 0.70710678118654752f));
                    Cb[(size_t)row * ldc + col] = f2b(v);
                }
            }
        }
    }
}

// ---------------------------------------------------------------- attention v3: bf16 K/V, double-buffered LDS tiles
__global__ __launch_bounds__(256) void attn_kernel(const unsigned short* __restrict__ QKV,
                                                   const int* __restrict__ idx_j,
                                                   const float* __restrict__ d_ij,
                                                   const void* __restrict__ mask,
                                                   const float* __restrict__ shifts,
                                                   const float* __restrict__ Wrb,
                                                   const float* __restrict__ brb,
                                                   const int* __restrict__ flag,
                                                   unsigned short* __restrict__ Ub) {
    __shared__ unsigned short Kt[2][16][280];  // 17.9 KB, double-buffered K/V tiles (bf16)
    __shared__ float rad[Mm][36];              // 9.2 KB
    __shared__ float att[Hh][Mm];              // 2 KB
    __shared__ float attbar[Mm];
    __shared__ int   jl[Mm];
    __shared__ float dv[Mm];
    __shared__ int   maskf[Mm];
    __shared__ float shs[Rr];

    int row = blockIdx.x;
    int b = row >> 9;                  // N=512
    int tid = threadIdx.x;
    bool boolmask = (*flag != 0);

    // prologue small loads (disjoint thread ranges)
    if (tid < Mm) jl[tid] = idx_j[row * Mm + tid];
    else if (tid < 128) { int m = tid - 64; dv[m] = d_ij[row * Mm + m]; }
    else if (tid < 160) shs[tid - 128] = shifts[tid - 128];
    else if (tid >= 192) {
        int m = tid - 192;
        maskf[m] = boolmask ? (int)((const unsigned char*)mask)[row * Mm + m]
                            : ((const int*)mask)[row * Mm + m];
    }

    // score role: pair p = tid>>1; (m = p&15 per tile, h = p>>4); half covers 16 of 32 dims
    int half = tid & 1;
    int p = tid >> 1;
    int hh = p >> 4;          // 0..7
    int ml = p & 15;          // 0..15
    float qf[16];
    {
        const unsigned short* qrow = QKV + (size_t)row * 768 + hh * 32 + half * 16;
        ushort8 q0 = *reinterpret_cast<const ushort8*>(qrow);
        ushort8 q1 = *reinterpret_cast<const ushort8*>(qrow + 8);
        #pragma unroll
        for (int i = 0; i < 8; ++i) { qf[i] = b2f(q0[i]); qf[8 + i] = b2f(q1[i]); }
    }
    float4 wreg[4];
    #pragma unroll
    for (int c = 0; c < 4; ++c)
        wreg[c] = *reinterpret_cast<const float4*>(Wrb + hh * Rr + half * 16 + c * 4);
    float brbh = brb[hh];
    __syncthreads();

    // coalesced gather-stage of 16 bf16 rows (512B each); seg: 256=K, 512=V
    auto stage = [&](int t, int seg, int buf) {
        #pragma unroll
        for (int q = 0; q < 2; ++q) {
            int chunk = q * 256 + tid;
            int r = chunk >> 5, s = chunk & 31;
            int j = jl[t * 16 + r];
            const uint4* src = reinterpret_cast<const uint4*>(QKV + (size_t)(b * Nn + j) * 768 + seg);
            uint4 v = src[s];
            *reinterpret_cast<uint4*>(&Kt[buf][r][s * 8]) = v;
        }
    };

    // radial basis + stage K tile 0
    #pragma unroll
    for (int it = 0; it < 8; ++it) {
        int i = tid + it * 256;
        int m = i >> 5, r = i & 31;
        float t = dv[m] - shs[r];
        rad[m][r] = expf(-4.0f * t * t);
    }
    stage(0, 256, 0);
    __syncthreads();

    // pass 1: scores, double-buffered
    for (int t = 0; t < 4; ++t) {
        if (t < 3) stage(t + 1, 256, (t + 1) & 1);
        int buf = t & 1;
        const unsigned short* kr = &Kt[buf][ml][hh * 32 + half * 16];
        ushort8 k0 = *reinterpret_cast<const ushort8*>(kr);
        ushort8 k1 = *reinterpret_cast<const ushort8*>(kr + 8);
        float accK = 0.f;
        #pragma unroll
        for (int i = 0; i < 8; ++i) accK = fmaf(qf[i], b2f(k0[i]), accK);
        #pragma unroll
        for (int i = 0; i < 8; ++i) accK = fmaf(qf[8 + i], b2f(k1[i]), accK);
        float accR = 0.f;
        #pragma unroll
        for (int c = 0; c < 4; ++c) {
            float4 rv = *reinterpret_cast<const float4*>(&rad[t * 16 + ml][half * 16 + c * 4]);
            accR += wreg[c].x * rv.x + wreg[c].y * rv.y + wreg[c].z * rv.z + wreg[c].w * rv.w;
        }
        float tv = accK * 0.17677669529663687f + accR;
        tv += __shfl_xor(tv, 1);
        if (!half) {
            int m = t * 16 + ml;
            att[hh][m] = maskf[m] ? -INFINITY : (tv + brbh);
        }
        __syncthreads();
    }

    // softmax over m per head + stage V tile 0 into buf0
    {
        int h = tid >> 5, l = tid & 31;
        float s0 = att[h][l], s1 = att[h][l + 32];
        float mx = fmaxf(s0, s1);
        #pragma unroll
        for (int off = 16; off; off >>= 1) mx = fmaxf(mx, __shfl_xor(mx, off, 32));
        float e0 = 0.f, e1 = 0.f;
        if (mx != -INFINITY) {
            e0 = expf(s0 - mx);
            e1 = expf(s1 - mx);
        }
        float sm = e0 + e1;
        #pragma unroll
        for (int off = 16; off; off >>= 1) sm += __shfl_xor(sm, off, 32);
        float inv = sm > 0.f ? 1.f / sm : 0.f;
        att[h][l] = e0 * inv;
        att[h][l + 32] = e1 * inv;
    }
    stage(0, 512, 0);
    __syncthreads();

    // pass 2: context, double-buffered; attbar folded into t=0
    float ctx = 0.f;
    int h2 = tid >> 5, d0 = tid & 31;
    for (int t = 0; t < 4; ++t) {
        if (t < 3) stage(t + 1, 512, (t + 1) & 1);
        int buf = t & 1;
        #pragma unroll
        for (int m = 0; m < 16; ++m)
            ctx = fmaf(att[h2][t * 16 + m], b2f(Kt[buf][m][h2 * 32 + d0]), ctx);
        if (t == 0 && tid < Mm) {
            float sv = 0.f;
            #pragma unroll
            for (int h = 0; h < Hh; ++h) sv += att[h][tid];
            attbar[tid] = sv * 0.125f;
        }
        __syncthreads();
    }

    // write context
    Ub[(size_t)row * KOUT + Ff + tid] = f2b(ctx);

    // radial context: pair-split over m
    if (tid < 64) {
        int g = tid >> 1;
        float acc = 0.f;
        #pragma unroll
        for (int i = 0; i < 32; ++i) {
            int m = half * 32 + i;
            acc = fmaf(attbar[m], rad[m][g], acc);
        }
        acc += __shfl_xor(acc, 1);
        if (!half) Ub[(size_t)row * KOUT + 2 * Ff + g] = f2b(acc);
    }
}

// ---------------------------------------------------------------- residual + bias + S partials + LN (wave per row)
template<int S, int WB>
__global__ __launch_bounds__(256) void add_ln_c(const float* __restrict__ x0,
                                                const float* __restrict__ part, size_t pstride,
                                                const float* __restrict__ bias,
                                                const float* __restrict__ g,
                                                const float* __restrict__ be,
                                                float* __restrict__ outp,
                                                unsigned short* __restrict__ xb) {
    int tid = threadIdx.x;
    int wave = tid >> 6, lane = tid & 63;
    int row = blockIdx.x * 4 + wave;
    size_t off = (size_t)row * Ff + lane * 4;
    float4 v = *reinterpret_cast<const float4*>(x0 + off);
    float4 bb = *reinterpret_cast<const float4*>(bias + lane * 4);
    v.x += bb.x; v.y += bb.y; v.z += bb.z; v.w += bb.w;
    #pragma unroll
    for (int s = 0; s < S; ++s) {
        float4 p = *reinterpret_cast<const float4*>(part + (size_t)s * pstride + off);
        v.x += p.x; v.y += p.y; v.z += p.z; v.w += p.w;
    }
    float sm = v.x + v.y + v.z + v.w;
    #pragma unroll
    for (int o = 32; o; o >>= 1) sm += __shfl_xor(sm, o, 64);
    float mu = sm * (1.f / Ff);
    float4 c = {v.x - mu, v.y - mu, v.z - mu, v.w - mu};
    float s2 = c.x * c.x + c.y * c.y + c.z * c.z + c.w * c.w;
    #pragma unroll
    for (int o = 32; o; o >>= 1) s2 += __shfl_xor(s2, o, 64);
    float inv = rsqrtf(s2 * (1.f / Ff) + 1e-5f);
    float4 gg = *reinterpret_cast<const float4*>(g + lane * 4);
    float4 ee = *reinterpret_cast<const float4*>(be + lane * 4);
    float4 r;
    r.x = c.x * inv * gg.x + ee.x;
    r.y = c.y * inv * gg.y + ee.y;
    r.z = c.z * inv * gg.z + ee.z;
    r.w = c.w * inv * gg.w + ee.w;
    *reinterpret_cast<float4*>(outp + off) = r;
    if (WB) {
        ushort4 u;
        u.x = f2b(r.x); u.y = f2b(r.y); u.z = f2b(r.z); u.w = f2b(r.w);
        *reinterpret_cast<ushort4*>(&xb[off]) = u;
    }
}

// ---------------------------------------------------------------- launch
extern "C" void kernel_launch(void* const* d_in, const int* in_sizes, int n_in,
                              void* d_out, int out_size, void* d_ws, size_t ws_size,
                              hipStream_t stream) {
    const float* a       = (const float*)d_in[0];
    const float* charges = (const float*)d_in[1];
    const int*   idx_j   = (const int*)  d_in[2];
    const float* d_ij    = (const float*)d_in[3];
    const void*  mask    =               d_in[4];
    const float* shifts  = (const float*)d_in[5];
    const float* Wq   = (const float*)d_in[6];  const float* bq   = (const float*)d_in[7];
    const float* Wk   = (const float*)d_in[8];  const float* bk   = (const float*)d_in[9];
    const float* Wv   = (const float*)d_in[10]; const float* bv   = (const float*)d_in[11];
    const float* Wrb  = (const float*)d_in[12]; const float* brb  = (const float*)d_in[13];
    const float* Wout = (const float*)d_in[14]; const float* bout = (const float*)d_in[15];
    const float* g1   = (const float*)d_in[16]; const float* b1   = (const float*)d_in[17];
    const float* g2   = (const float*)d_in[18]; const float* b2   = (const float*)d_in[19];
    const float* Wf1  = (const float*)d_in[20]; const float* bf1  = (const float*)d_in[21];
    const float* Wf2  = (const float*)d_in[22]; const float* bf2  = (const float*)d_in[23];
    float* outp = (float*)d_out;

    float* ws   = (float*)d_ws;
    int*   flag = (int*)d_ws;
    // ws layout (floats): flag(1024) | part (1,048,576) | xbuf (524,288) | bf16 arena (5,472,256 ushorts)
    float* part = ws + 1024;
    float* xbuf = part + 1048576;
    unsigned short* arena = (unsigned short*)(xbuf + 524288);
    unsigned short* centerb = arena + OFF_CENTER;
    unsigned short* Wqkvb   = arena + OFF_WQKV;
    unsigned short* Woutb   = arena + OFF_WOUT;
    unsigned short* Wf1b    = arena + OFF_WF1;
    unsigned short* Wf2b    = arena + OFF_WF2;
    unsigned short* Ub      = arena + OFF_U;
    unsigned short* xb      = arena + OFF_XB;
    unsigned short* ffhb    = arena + OFF_FFH;
    unsigned short* QKVB16  = arena + OFF_QKVB;

    hipMemsetAsync(flag, 0, sizeof(int), stream);
    prep<<<CONV_BLK + A2U_BLK + MSK_BLK, 256, 0, stream>>>(
        a, charges, Wq, Wk, Wv, Wout, Wf1, Wf2, (const unsigned char*)mask, flag, arena);

    // QKV: [2048 x 768], K=288 (9 tiles), bias fused, bf16 out
    gemm_mfma<9, 1, 1><<<dim3(12, 32, 1), 256, 0, stream>>>(
        centerb, KINP, Wqkvb, KINP, bq, bk, bv, nullptr, QKVB16, 768, 0);

    attn_kernel<<<ROWS, 256, 0, stream>>>(QKVB16, idx_j, d_ij, mask, shifts, Wrb, brb, flag, Ub);

    // Wout: [2048 x 256], K=544 (17 tiles), split 2
    gemm_mfma<17, 2, 0><<<dim3(4, 32, 2), 256, 0, stream>>>(
        Ub, KOUT, Woutb, KOUT, nullptr, nullptr, nullptr, part, nullptr, Ff, (size_t)ROWS * Ff);
    add_ln_c<2, 1><<<ROWS / 4, 256, 0, stream>>>(a, part, (size_t)ROWS * Ff, bout, g1, b1, xbuf, xb);

    // FFN1: [2048 x 512], K=256 (8 tiles), GELU+bias epilogue -> bf16
    gemm_mfma<8, 1, 2><<<dim3(8, 32, 1), 256, 0, stream>>>(
        xb, Ff, Wf1b, Ff, bf1, nullptr, nullptr, nullptr, ffhb, FFNH, 0);

    // FFN2: [2048 x 256], K=512 (16 tiles), split 2
    gemm_mfma<16, 2, 0><<<dim3(4, 32, 2), 256, 0, stream>>>(
        ffhb, FFNH, Wf2b, FFNH, nullptr, nullptr, nullptr, part, nullptr, Ff, (size_t)ROWS * Ff);
    add_ln_c<2, 0><<<ROWS / 4, 256, 0, stream>>>(xbuf, part, (size_t)ROWS * Ff, bf2, g2, b2, outp, nullptr);
}